// Round 14
// baseline (614.386 us; speedup 1.0000x reference)
//
#include <hip/hip_runtime.h>
#include <hip/hip_bf16.h>
#include <math.h>

// Problem constants
#define Bsz 2048
#define T1  9      // T-1
#define Hs  512
#define IN2 15

typedef __bf16 bf16x8 __attribute__((ext_vector_type(8)));
typedef float  f32x4  __attribute__((ext_vector_type(4)));
typedef __hip_bfloat16 bf16;

// ---------------------------------------------------------------------------
// Algebra (verified rounds 1-13):
//  * enc softmax over features invariant to (h@Wh+s@Ws) scalar => a1/a2
//    constant over time; Wh/Ws dead.
//  * dec attention: score = Xe.v + const(b), v = W2@W1x => beta/context
//    constant across decoder steps; rank-1 y_tilde term folded into epilogue.
// Precision: bf16x1 (validated R13: absmax 0.00195 == bf16x2's, 3x margin).
// R13 state: 538us; every 128x128 tiling gives 512 blocks = 2 waves/SIMD ->
// latency-bound ~2x above LDS+MFMA overlap model. THIS ROUND: IN-BLOCK
// SPLIT-K. 512-thread blocks, 8 waves in 2 K-groups (waves 0-3: K[0:K/2],
// 4-7: K[K/2:K]); each group runs the proven single-barrier dbuf loop on its
// own LDS buffers. Same LDS traffic/element, half the barrier iterations,
// 4 waves/SIMD. Epilogue: group1 spills acc via LDS f32x4 chunks (2-way-free
// banks), group0 reduces + gates. Encoder KPAD 544->576 for even 9/9 split.
// Weight layout n' = (j/16)*64 + g*16 + (j%16): a 64-wide wave n' window holds
// all 4 gates for 16 j's -> fully in-register gate epilogue.
// ---------------------------------------------------------------------------

#define BMT 128   // rows (batch) per block
#define BNP 128   // n' cols per block

struct GA {
  const bf16* Ahi;   // B x HG   activations (hi)
  const bf16* Axhi;  // B x 16   x-part for this t (enc) or null
  const bf16* Whi;   // 4HG x Kpad, n'-ordered
  const float* bsum; // 4HG, n'-ordered (bih+bhh)
  const float* wihp; // 4HG, n'-ordered rank-1 weights (dec) or null
  const float* ytp;  // rank-1 activation column y_tilde (dec) or null
  float* c;          // B x HG cell state (in/out)
  bf16* Hhi;         // B x HG h out
  float* hf;         // optional fp32 h out (Xe slice / final d) or null
  int hf_stride;
  int ytstride;
};

template<int HG, int KPAD, bool HAS_X, int ZD>
__global__ __launch_bounds__(512, 2)
void lstm2_k(GA a0, GA a1) {
  constexpr int KT2 = KPAD / 64;      // K-tiles per group
  constexpr int GX = (4 * HG) / BNP;
  constexpr int GY = Bsz / BMT;       // 16
  constexpr int NWG = GX * GY * ZD;
  constexpr int Q = NWG / 8;

  // [dbuf][group][4096 bf16] each; 32 KB + 32 KB = 64 KB/block
  __shared__ __align__(16) unsigned short As[2][2][4096];
  __shared__ __align__(16) unsigned short Bh[2][2][4096];

  const int tid = threadIdx.x;
  // bijective XCD swizzle (NWG % 8 == 0); mb fastest -> consecutive blocks on
  // one XCD share one weight n-panel in that XCD's L2.
  const int orig = blockIdx.x + GX * (blockIdx.y + GY * blockIdx.z);
  const int swz = (orig & 7) * Q + (orig >> 3);
  // ---- SCALAR field selects (block-uniform -> SGPR cselect, no scratch) ----
  const bool sel = (ZD == 2) && (swz >= GX * GY);
  const bf16* __restrict__ Ahi  = sel ? a1.Ahi  : a0.Ahi;
  const bf16* __restrict__ Axhi = sel ? a1.Axhi : a0.Axhi;
  const bf16* __restrict__ Whi  = sel ? a1.Whi  : a0.Whi;
  const float* __restrict__ bsum = sel ? a1.bsum : a0.bsum;
  const float* __restrict__ wihp = sel ? a1.wihp : a0.wihp;
  const float* __restrict__ ytp  = sel ? a1.ytp  : a0.ytp;
  float* __restrict__ cst = sel ? a1.c   : a0.c;
  bf16*  __restrict__ Hhi = sel ? a1.Hhi : a0.Hhi;
  float* __restrict__ hf  = sel ? a1.hf  : a0.hf;
  const int hf_stride = sel ? a1.hf_stride : a0.hf_stride;
  const int ytstride  = sel ? a1.ytstride  : a0.ytstride;

  const int rem = (ZD == 2) ? (swz & (GX * GY - 1)) : swz;
  const int nb = rem / GY;
  const int mb = rem % GY;
  const int m0 = mb * BMT, n0 = nb * BNP;

  // staging: threads [0,255] stage group0's K-tiles, [256,511] group1's.
  const int tl = tid & 255;
  const int grp = tid >> 8;           // == wave>=4
  const int kcb = (tl & 3) * 8;
  const int ra = tl >> 2;   // 0..63

  uint4 s0, s1, s2, s5;   // named staging regs
  auto stage_load = [&](int ktt) {    // ktt is group-local tile index
    const int ke = (ktt + grp * KT2) * 32 + kcb;
    if (!HAS_X || ke < HG) {
      const size_t ag = (size_t)(m0 + ra) * HG + ke;
      s0 = *reinterpret_cast<const uint4*>(Ahi + ag);
      s5 = *reinterpret_cast<const uint4*>(Ahi + ag + (size_t)64 * HG);
    } else if (ke < HG + 16) {
      s0 = *reinterpret_cast<const uint4*>(Axhi + (size_t)(m0 + ra) * 16 + (ke - HG));
      s5 = *reinterpret_cast<const uint4*>(Axhi + (size_t)(m0 + ra + 64) * 16 + (ke - HG));
    } else {
      s0.x = s0.y = s0.z = s0.w = 0u;
      s5 = s0;
    }
    const size_t bg = (size_t)(n0 + ra) * KPAD + ke;
    s1 = *reinterpret_cast<const uint4*>(Whi + bg);
    s2 = *reinterpret_cast<const uint4*>(Whi + bg + (size_t)64 * KPAD);
  };
  // XOR-swizzled write offsets (16B-chunk granularity); (ra+64)&7 == ra&7
  const int wofA = (ra * 32 + kcb) ^ ((ra & 7) << 3);
  const int wofB = wofA + 2048;
  auto stage_write = [&](int p) {
    *reinterpret_cast<uint4*>(&As[p][grp][wofA]) = s0;
    *reinterpret_cast<uint4*>(&As[p][grp][wofB]) = s5;
    *reinterpret_cast<uint4*>(&Bh[p][grp][wofA]) = s1;
    *reinterpret_cast<uint4*>(&Bh[p][grp][wofB]) = s2;
  };

  const int lane = tid & 63;
  const int wv = tid >> 6;            // 0..7; wv>>2 == grp
  const int wl = wv & 3;
  const int wr = wl >> 1, wc = wl & 1;  // per-group 2x2 wave grid, 64x64 each
  const int l15 = lane & 15;
  const int lk = (lane >> 4) * 8;

  // XOR-swizzled read offsets; +16 rows = +512 elems (XOR bits untouched)
  const int rswz = (l15 & 7) << 3;
  const int aoff0 = (((wr * 64 + l15) * 32) + lk) ^ rswz;
  const int boff0 = (((wc * 64 + l15) * 32) + lk) ^ rswz;

  f32x4 acc[4][4] = {};

  // prologue: tile 0 into buf0 (pre-barrier write is safe), tile 1 staged
  stage_load(0);
  stage_write(0);
  stage_load(1);

  for (int kt = 0; kt < KT2; ++kt) {
    __syncthreads();  // all prior reads of buf[(kt+1)&1] done; tile kt visible
    if (kt + 1 < KT2) stage_write((kt + 1) & 1);  // regs hold tile kt+1
    const int p = kt & 1;

    bf16x8 ah[4];
#pragma unroll
    for (int mi = 0; mi < 4; ++mi)
      ah[mi] = __builtin_bit_cast(bf16x8,
                 *reinterpret_cast<const uint4*>(&As[p][grp][aoff0 + mi * 512]));
    if (kt + 2 < KT2) stage_load(kt + 2);  // overlap with MFMA below
#pragma unroll
    for (int ni = 0; ni < 4; ++ni) {
      bf16x8 bhv = __builtin_bit_cast(bf16x8,
                     *reinterpret_cast<const uint4*>(&Bh[p][grp][boff0 + ni * 512]));
#pragma unroll
      for (int mi = 0; mi < 4; ++mi)
        acc[mi][ni] = __builtin_amdgcn_mfma_f32_16x16x32_bf16(ah[mi], bhv, acc[mi][ni], 0, 0, 0);
    }
  }

  // ---- cross-group reduction: group1 spills acc via LDS, group0 reduces ----
  __syncthreads();  // all K-loop LDS reads complete; buffers reusable
  {
    float* region = (wl < 2) ? reinterpret_cast<float*>(&As[0][0][0]) + wl * 4096
                             : reinterpret_cast<float*>(&Bh[0][0][0]) + (wl - 2) * 4096;
    if (grp == 1) {
#pragma unroll
      for (int mi = 0; mi < 4; ++mi)
#pragma unroll
        for (int ni = 0; ni < 4; ++ni)
          *reinterpret_cast<f32x4*>(region + (mi * 4 + ni) * 256 + lane * 4) = acc[mi][ni];
    }
    __syncthreads();
    if (grp == 0) {
#pragma unroll
      for (int mi = 0; mi < 4; ++mi)
#pragma unroll
        for (int ni = 0; ni < 4; ++ni) {
          f32x4 o = *reinterpret_cast<const f32x4*>(region + (mi * 4 + ni) * 256 + lane * 4);
          acc[mi][ni] += o;
        }
    }
  }
  if (grp != 0) return;

  // Epilogue (group0 only): ni == gate g; j = nb*32 + wc*16 + l15
  const int j = nb * 32 + wc * 16 + l15;
  const int npb = nb * 128 + wc * 64 + l15;
  const float bs0 = bsum[npb], bs1 = bsum[npb + 16];
  const float bs2 = bsum[npb + 32], bs3 = bsum[npb + 48];
  float w0 = 0.f, w1 = 0.f, w2 = 0.f, w3 = 0.f;
  if (!HAS_X) {
    w0 = wihp[npb]; w1 = wihp[npb + 16];
    w2 = wihp[npb + 32]; w3 = wihp[npb + 48];
  }
#pragma unroll
  for (int mi = 0; mi < 4; ++mi) {
#pragma unroll
    for (int r = 0; r < 4; ++r) {
      const int rowl = wr * 64 + mi * 16 + (lane >> 4) * 4 + r;
      const size_t rowg = m0 + rowl;
      float gi = acc[mi][0][r] + bs0;
      float gf = acc[mi][1][r] + bs1;
      float gg = acc[mi][2][r] + bs2;
      float go = acc[mi][3][r] + bs3;
      if (!HAS_X) {
        const float yv = ytp[rowg * ytstride];
        gi += yv * w0; gf += yv * w1; gg += yv * w2; go += yv * w3;
      }
      const float i_ = 1.f / (1.f + __expf(-gi));
      const float f_ = 1.f / (1.f + __expf(-gf));
      const float tg = __expf(2.f * gg);
      const float g_ = (tg - 1.f) / (tg + 1.f);
      const float o_ = 1.f / (1.f + __expf(-go));
      const size_t idx = rowg * HG + j;
      const float cn = f_ * cst[idx] + i_ * g_;
      cst[idx] = cn;
      const float tc = __expf(2.f * cn);
      const float hn = o_ * (tc - 1.f) / (tc + 1.f);
      Hhi[idx] = __float2bfloat16(hn);
      if (hf) hf[rowg * hf_stride + j] = hn;
    }
  }
}

// All three weight rebuilds in ONE dispatch (block-range dispatch).
// Composite n'-interleaved order, hi only; bsum; wihp.
// set0: enc0 (576 blocks, Kpad=576), set1: enc1 (576), set2: dec (2048).
__global__ void build_all_w_k(
    const float* __restrict__ W0hh, const float* __restrict__ W0ih,
    const float* __restrict__ b0ih, const float* __restrict__ b0hh,
    const float* __restrict__ W1hh, const float* __restrict__ W1ih,
    const float* __restrict__ b1ih, const float* __restrict__ b1hh,
    const float* __restrict__ Wdhh, const float* __restrict__ Wdih,
    const float* __restrict__ bdih, const float* __restrict__ bdhh,
    bf16* __restrict__ W0hi, bf16* __restrict__ W1hi, bf16* __restrict__ Wdhi,
    float* __restrict__ bs0, float* __restrict__ bs1,
    float* __restrict__ bsd, float* __restrict__ wihp) {
  const int bid = blockIdx.x;
  const float *Whh, *Wih, *bih, *bhh;
  bf16 *Whi;
  float *bsum, *wp;
  int HG, nx, Kpad, base;
  if (bid < 576) {
    Whh = W0hh; Wih = W0ih; bih = b0ih; bhh = b0hh;
    Whi = W0hi; bsum = bs0; wp = nullptr;
    HG = Hs; nx = 16; Kpad = 576; base = 0;
  } else if (bid < 1152) {
    Whh = W1hh; Wih = W1ih; bih = b1ih; bhh = b1hh;
    Whi = W1hi; bsum = bs1; wp = nullptr;
    HG = Hs; nx = 15; Kpad = 576; base = 576;
  } else {
    Whh = Wdhh; Wih = Wdih; bih = bdih; bhh = bdhh;
    Whi = Wdhi; bsum = bsd; wp = wihp;
    HG = 2 * Hs; nx = 0; Kpad = 1024; base = 1152;
  }
  const int chunks = Kpad >> 3;
  const int idx = (bid - base) * 256 + threadIdx.x;
  if (idx >= 4 * HG * chunks) return;
  const int np = idx / chunks;
  const int k0 = (idx - np * chunks) << 3;
  const int g = (np >> 4) & 3;
  const int jj = ((np >> 6) << 4) + (np & 15);
  const int norig = g * HG + jj;
  float v[8];
  if (k0 + 8 <= HG) {
    const float4* s = reinterpret_cast<const float4*>(Whh + (size_t)norig * HG + k0);
    float4 v0 = s[0], v1 = s[1];
    v[0] = v0.x; v[1] = v0.y; v[2] = v0.z; v[3] = v0.w;
    v[4] = v1.x; v[5] = v1.y; v[6] = v1.z; v[7] = v1.w;
  } else {
#pragma unroll
    for (int u = 0; u < 8; ++u) {
      const int k = k0 + u;
      v[u] = (k < HG) ? Whh[(size_t)norig * HG + k]
                      : ((k - HG < nx) ? Wih[(size_t)norig * nx + (k - HG)] : 0.f);
    }
  }
  unsigned short hh[8];
#pragma unroll
  for (int u = 0; u < 8; ++u) {
    const bf16 h = __float2bfloat16(v[u]);
    hh[u] = *reinterpret_cast<const unsigned short*>(&h);
  }
  const size_t off = (size_t)np * Kpad + k0;
  *reinterpret_cast<uint4*>((unsigned short*)Whi + off) = *reinterpret_cast<uint4*>(hh);
  if (k0 == 0) {
    bsum[np] = bih[norig] + bhh[norig];
    if (wp) wp[np] = Wih[norig];  // dec: Wih is (8H,1)
  }
}

// Per-batch encoder attention weights (time-invariant) -> x_tilde tables.
__global__ void prep_attn_k(const float* __restrict__ X, const float* __restrict__ yp,
                            const float* __restrict__ encW, const float* __restrict__ encb,
                            bf16* __restrict__ x1h, bf16* __restrict__ x2h) {
  const int b = blockIdx.x;
  const int tid = threadIdx.x;  // 64
  __shared__ float wf[T1], ypb[T1];
  __shared__ float s1[16], s2[IN2], e1[16], e2[IN2];
  if (tid < T1) {
    wf[tid] = encW[2 * Hs + tid];
    ypb[tid] = yp[(size_t)b * T1 + tid];
  }
  __syncthreads();
  const float bb = encb[0];
  if (tid < 16) {
    float acc = bb;
    for (int t = 0; t < T1; ++t) {
      float xv = (tid < IN2) ? X[(size_t)b * (T1 * IN2) + t * IN2 + tid] : ypb[t];
      acc += xv * wf[t];
    }
    s1[tid] = acc;
  } else if (tid < 16 + IN2) {
    const int k = tid - 16;
    float acc = bb;
    for (int t = 0; t < T1; ++t)
      acc += X[(size_t)b * (T1 * IN2) + t * IN2 + k] * ypb[t] * wf[t];
    s2[k] = acc;
  }
  __syncthreads();
  if (tid < 16) {
    float m = -1e30f;
    for (int k = 0; k < 16; ++k) m = fmaxf(m, s1[k]);
    e1[tid] = expf(s1[tid] - m);
  } else if (tid < 16 + IN2) {
    const int k = tid - 16;
    float m = -1e30f;
    for (int kk = 0; kk < IN2; ++kk) m = fmaxf(m, s2[kk]);
    e2[k] = expf(s2[k] - m);
  }
  __syncthreads();
  if (tid < 16) {
    float sum = 0.f;
    for (int k = 0; k < 16; ++k) sum += e1[k];
    const float a = e1[tid] / sum;
    for (int t = 0; t < T1; ++t) {
      float xv = (tid < IN2) ? X[(size_t)b * (T1 * IN2) + t * IN2 + tid] : ypb[t];
      x1h[((size_t)t * Bsz + b) * 16 + tid] = __float2bfloat16(a * xv);
    }
  } else if (tid < 16 + IN2) {
    const int k = tid - 16;
    float sum = 0.f;
    for (int kk = 0; kk < IN2; ++kk) sum += e2[kk];
    const float a = e2[k] / sum;
    for (int t = 0; t < T1; ++t)
      x2h[((size_t)t * Bsz + b) * 16 + k] =
          __float2bfloat16(a * X[(size_t)b * (T1 * IN2) + t * IN2 + k] * ypb[t]);
  } else if (tid == 31) {
    const bf16 z = __float2bfloat16(0.f);
    for (int t = 0; t < T1; ++t) x2h[((size_t)t * Bsz + b) * 16 + 15] = z;
  }
}

// v[dd] = sum_h dec_attn2_W[0,h] * dec_attn1_W[h, 4H+dd]
// Wave-per-output GEMV: grid 1024 x 64 threads, lane l sums 8 h's, shfl-reduce.
__global__ void prep_v_k(const float* __restrict__ A1W, const float* __restrict__ A2W,
                         float* __restrict__ v) {
  const int dd = blockIdx.x;      // 0..1023
  const int l = threadIdx.x;      // 0..63
  float acc = 0.f;
#pragma unroll
  for (int k = 0; k < 8; ++k) {
    const int h = l + 64 * k;
    acc += A2W[h] * A1W[(size_t)h * (6 * Hs) + 4 * Hs + dd];
  }
#pragma unroll
  for (int off = 32; off > 0; off >>= 1) acc += __shfl_down(acc, off);
  if (l == 0) v[dd] = acc;
}

// Decoder attention (step-invariant): float4 + shuffle reductions; Xe tile
// cached in registers between the score and context passes.
__global__ void dec_ctx_k(const float* __restrict__ Xe, const float* __restrict__ v,
                          const float* __restrict__ yp, const float* __restrict__ fcW,
                          const float* __restrict__ fcb,
                          float* __restrict__ ctx, float* __restrict__ yt) {
  const int b = blockIdx.x;
  const int tid = threadIdx.x;  // 256
  const int lane = tid & 63, wid = tid >> 6;
  const float* xb = Xe + (size_t)b * (T1 * 2 * Hs);
  const int d0 = tid * 4;       // 256*4 = 1024 = 2*Hs
  const float4 v4 = *reinterpret_cast<const float4*>(v + d0);
  float4 x4[T1];
  float s[T1];
#pragma unroll
  for (int t = 0; t < T1; ++t) {
    x4[t] = *reinterpret_cast<const float4*>(xb + t * 2 * Hs + d0);
    s[t] = x4[t].x * v4.x + x4[t].y * v4.y + x4[t].z * v4.z + x4[t].w * v4.w;
  }
  __shared__ float part[T1][4];
  __shared__ float score[T1];
  __shared__ float tot2[4];
  __shared__ float cfs;
#pragma unroll
  for (int t = 0; t < T1; ++t) {
    float r = s[t];
#pragma unroll
    for (int off = 32; off > 0; off >>= 1) r += __shfl_down(r, off);
    if (lane == 0) part[t][wid] = r;
  }
  __syncthreads();
  if (tid < T1) score[tid] = part[tid][0] + part[tid][1] + part[tid][2] + part[tid][3];
  __syncthreads();
  float mx = -1e30f;
#pragma unroll
  for (int t = 0; t < T1; ++t) mx = fmaxf(mx, score[t]);
  float e[T1];
  float sum = 0.f;
#pragma unroll
  for (int t = 0; t < T1; ++t) { e[t] = expf(score[t] - mx); sum += e[t]; }
  const float inv = 1.f / sum;
  float4 c4 = {0.f, 0.f, 0.f, 0.f};
#pragma unroll
  for (int t = 0; t < T1; ++t) {
    c4.x += e[t] * x4[t].x; c4.y += e[t] * x4[t].y;
    c4.z += e[t] * x4[t].z; c4.w += e[t] * x4[t].w;
  }
  c4.x *= inv; c4.y *= inv; c4.z *= inv; c4.w *= inv;
  *reinterpret_cast<float4*>(ctx + (size_t)b * 2 * Hs + d0) = c4;
  const float4 f4 = *reinterpret_cast<const float4*>(fcW + d0);
  float fcacc = c4.x * f4.x + c4.y * f4.y + c4.z * f4.z + c4.w * f4.w;
#pragma unroll
  for (int off = 32; off > 0; off >>= 1) fcacc += __shfl_down(fcacc, off);
  if (lane == 0) tot2[wid] = fcacc;
  __syncthreads();
  if (tid == 0) cfs = tot2[0] + tot2[1] + tot2[2] + tot2[3] + fcb[0];
  __syncthreads();
  if (tid < T1) yt[(size_t)b * T1 + tid] = cfs + yp[(size_t)b * T1 + tid] * fcW[2 * Hs];
}

__global__ void final_out_k(const float* __restrict__ dfin, const float* __restrict__ ctx,
                            const float* __restrict__ Wfin, const float* __restrict__ bfin,
                            float* __restrict__ out) {
  const int b = blockIdx.x;
  const int tid = threadIdx.x;  // 256
  const int lane = tid & 63, wid = tid >> 6;
  const int d0 = tid * 4;
  const float4 a4 = *reinterpret_cast<const float4*>(dfin + (size_t)b * 2 * Hs + d0);
  const float4 w4 = *reinterpret_cast<const float4*>(Wfin + d0);
  const float4 c4 = *reinterpret_cast<const float4*>(ctx + (size_t)b * 2 * Hs + d0);
  const float4 u4 = *reinterpret_cast<const float4*>(Wfin + 2 * Hs + d0);
  float acc = a4.x * w4.x + a4.y * w4.y + a4.z * w4.z + a4.w * w4.w
            + c4.x * u4.x + c4.y * u4.y + c4.z * u4.z + c4.w * u4.w;
#pragma unroll
  for (int off = 32; off > 0; off >>= 1) acc += __shfl_down(acc, off);
  __shared__ float red[4];
  if (lane == 0) red[wid] = acc;
  __syncthreads();
  if (tid == 0) out[b] = red[0] + red[1] + red[2] + red[3] + bfin[0];
}

extern "C" void kernel_launch(void* const* d_in, const int* in_sizes, int n_in,
                              void* d_out, int out_size, void* d_ws, size_t ws_size,
                              hipStream_t stream) {
  const float* X     = (const float*)d_in[0];
  const float* yp    = (const float*)d_in[1];
  const float* encW  = (const float*)d_in[2];
  const float* encb  = (const float*)d_in[3];
  const float* e0Wih = (const float*)d_in[4];
  const float* e0Whh = (const float*)d_in[5];
  const float* e0bih = (const float*)d_in[6];
  const float* e0bhh = (const float*)d_in[7];
  const float* e1Wih = (const float*)d_in[8];
  const float* e1Whh = (const float*)d_in[9];
  const float* e1bih = (const float*)d_in[10];
  const float* e1bhh = (const float*)d_in[11];
  const float* dA1W  = (const float*)d_in[12];
  const float* dA2W  = (const float*)d_in[14];
  const float* dWih  = (const float*)d_in[16];
  const float* dWhh  = (const float*)d_in[17];
  const float* dbih  = (const float*)d_in[18];
  const float* dbhh  = (const float*)d_in[19];
  const float* fcW   = (const float*)d_in[20];
  const float* fcb   = (const float*)d_in[21];
  const float* WfinW = (const float*)d_in[22];
  const float* Wfinb = (const float*)d_in[23];
  float* out = (float*)d_out;
  (void)in_sizes; (void)n_in; (void)out_size; (void)ws_size;

  char* wsb = (char*)d_ws;
  size_t off = 0;
  auto alloc = [&](size_t bytes) -> void* {
    void* p = wsb + off;
    off = (off + bytes + 255) & ~(size_t)255;
    return p;
  };
  const size_t BH  = (size_t)Bsz * Hs;
  const size_t BH2 = (size_t)Bsz * 2 * Hs;
  // ---- zero-init region (one memset per call) ----
  float* c1   = (float*)alloc(BH * 4);
  float* c2   = (float*)alloc(BH * 4);
  float* cdec = (float*)alloc(BH2 * 4);
  bf16* h1hi0 = (bf16*)alloc(BH * 2);
  bf16* h2hi0 = (bf16*)alloc(BH * 2);
  bf16* dhi0  = (bf16*)alloc(BH2 * 2);
  const size_t zero_bytes = off;
  // ---- rest ----
  bf16* h1hi1 = (bf16*)alloc(BH * 2);
  bf16* h2hi1 = (bf16*)alloc(BH * 2);
  bf16* dhi1  = (bf16*)alloc(BH2 * 2);
  bf16* W0hi  = (bf16*)alloc((size_t)2048 * 576 * 2);
  bf16* W1hi  = (bf16*)alloc((size_t)2048 * 576 * 2);
  bf16* Wdhi  = (bf16*)alloc((size_t)4096 * 1024 * 2);
  float* bs0  = (float*)alloc(2048 * 4);
  float* bs1  = (float*)alloc(2048 * 4);
  float* bsd  = (float*)alloc(4096 * 4);
  float* wihp = (float*)alloc(4096 * 4);
  bf16* x1h   = (bf16*)alloc((size_t)T1 * Bsz * 16 * 2);
  bf16* x2h   = (bf16*)alloc((size_t)T1 * Bsz * 16 * 2);
  float* Xe   = (float*)alloc((size_t)Bsz * T1 * 2 * Hs * 4);
  float* dfp  = (float*)alloc(BH2 * 4);
  float* ctx  = (float*)alloc(BH2 * 4);
  float* vv   = (float*)alloc(2 * Hs * 4);
  float* yt   = (float*)alloc((size_t)Bsz * T1 * 4);

  hipMemsetAsync(d_ws, 0, zero_bytes, stream);

  build_all_w_k<<<3200, 256, 0, stream>>>(
      e0Whh, e0Wih, e0bih, e0bhh, e1Whh, e1Wih, e1bih, e1bhh,
      dWhh, dWih, dbih, dbhh,
      W0hi, W1hi, Wdhi, bs0, bs1, bsd, wihp);
  prep_attn_k<<<Bsz, 64, 0, stream>>>(X, yp, encW, encb, x1h, x2h);
  prep_v_k<<<2 * Hs, 64, 0, stream>>>(dA1W, dA2W, vv);

  // ---- encoder: 9 steps, both branches per launch ----
  bf16 *h1c = h1hi0, *h1n = h1hi1;
  bf16 *h2c = h2hi0, *h2n = h2hi1;
  for (int t = 0; t < T1; ++t) {
    GA a0{h1c, x1h + (size_t)t * Bsz * 16, W0hi, bs0, nullptr, nullptr,
          c1, h1n, Xe + (size_t)t * 2 * Hs, T1 * 2 * Hs, 0};
    GA a1{h2c, x2h + (size_t)t * Bsz * 16, W1hi, bs1, nullptr, nullptr,
          c2, h2n, Xe + (size_t)t * 2 * Hs + Hs, T1 * 2 * Hs, 0};
    dim3 grid((4 * Hs) / BNP, Bsz / BMT, 2);
    lstm2_k<Hs, 576, true, 2><<<grid, 512, 0, stream>>>(a0, a1);
    bf16* tp;
    tp = h1c; h1c = h1n; h1n = tp;
    tp = h2c; h2c = h2n; h2n = tp;
  }

  dec_ctx_k<<<Bsz, 256, 0, stream>>>(Xe, vv, yp, fcW, fcb, ctx, yt);

  // ---- decoder: 9 steps ----
  bf16 *dc = dhi0, *dn = dhi1;
  for (int t = 0; t < T1; ++t) {
    GA a0{dc, nullptr, Wdhi, bsd, wihp, yt + t,
          cdec, dn, (t == T1 - 1) ? dfp : nullptr, 2 * Hs, T1};
    dim3 grid((8 * Hs) / BNP, Bsz / BMT, 1);
    lstm2_k<2 * Hs, 1024, false, 1><<<grid, 512, 0, stream>>>(a0, a0);
    bf16* tp = dc; dc = dn; dn = tp;
  }

  final_out_k<<<Bsz, 256, 0, stream>>>(dfp, ctx, WfinW, Wfinb, out);
}

// Round 15
// 537.915 us; speedup vs baseline: 1.1422x; 1.1422x over previous
//
#include <hip/hip_runtime.h>
#include <hip/hip_bf16.h>
#include <math.h>

// Problem constants
#define Bsz 2048
#define T1  9      // T-1
#define Hs  512
#define IN2 15

typedef __bf16 bf16x8 __attribute__((ext_vector_type(8)));
typedef float  f32x4  __attribute__((ext_vector_type(4)));
typedef __hip_bfloat16 bf16;

#define AS1C const __attribute__((address_space(1))) void*
#define AS3P __attribute__((address_space(3))) void*

// ---------------------------------------------------------------------------
// Algebra (verified rounds 1-14):
//  * enc softmax over features invariant to (h@Wh+s@Ws) scalar => a1/a2
//    constant over time; Wh/Ws dead.
//  * dec attention: score = Xe.v + const(b), v = W2@W1x => beta/context
//    constant across decoder steps; rank-1 y_tilde term folded into epilogue.
// Precision: bf16x1 (validated R13: absmax 0.00195, 3x margin).
// R14 split-K regressed (614us) -> revert to R13 geometry (538us, 128x128,
// 4 waves, single-barrier dbuf, XOR swizzle).
// THIS ROUND: global_load_lds staging (guide common-mistake #1, never tried).
// DMA writes LDS LINEARLY (wave base + lane*16); swizzle moved to the GLOBAL
// source address via the inverse chunk map (XOR is an involution):
//   chunk q -> c: c2=q2^q4, c1=q1^q3, c0=q0^c2, ra=c>>2, kc=c&3
// (algebraically verified). Read side identical to R13. Removes 4 ds_writes +
// 4 staging-reg waits per thread per kt. Single barrier/kt: loads for kt+1
// issued AFTER the barrier retiring reads of the target buffer; next barrier's
// compiler vmcnt(0) drain guarantees residency (m97 pattern).
// Encoder x-tables widened to stride 32 with prebuilt zero cols so the DMA
// tail needs no predication.
// Weight layout n' = (j/16)*64 + g*16 + (j%16): a 64-wide wave n' window holds
// all 4 gates for 16 j's -> fully in-register gate epilogue.
// ---------------------------------------------------------------------------

#define BMT 128   // rows (batch) per block
#define BNP 128   // n' cols per block

struct GA {
  const bf16* Ahi;   // B x HG   activations (hi)
  const bf16* Axhi;  // B x 32   x-part for this t (enc, zero-padded) or null
  const bf16* Whi;   // 4HG x Kpad, n'-ordered
  const float* bsum; // 4HG, n'-ordered (bih+bhh)
  const float* wihp; // 4HG, n'-ordered rank-1 weights (dec) or null
  const float* ytp;  // rank-1 activation column y_tilde (dec) or null
  float* c;          // B x HG cell state (in/out)
  bf16* Hhi;         // B x HG h out
  float* hf;         // optional fp32 h out (Xe slice / final d) or null
  int hf_stride;
  int ytstride;
};

template<int HG, int KPAD, bool HAS_X, int ZD>
__global__ __launch_bounds__(256, 2)
void lstm2_k(GA a0, GA a1) {
  constexpr int KT = KPAD / 32;
  constexpr int GX = (4 * HG) / BNP;
  constexpr int GY = Bsz / BMT;       // 16
  constexpr int NWG = GX * GY * ZD;
  constexpr int Q = NWG / 8;

  __shared__ __align__(16) unsigned short As[2][4096];
  __shared__ __align__(16) unsigned short Bh[2][4096];

  const int tid = threadIdx.x;
  // bijective XCD swizzle (NWG % 8 == 0); mb fastest -> consecutive blocks on
  // one XCD share one weight n-panel in that XCD's L2.
  const int orig = blockIdx.x + GX * (blockIdx.y + GY * blockIdx.z);
  const int swz = (orig & 7) * Q + (orig >> 3);
  // ---- SCALAR field selects (block-uniform -> SGPR cselect, no scratch) ----
  const bool sel = (ZD == 2) && (swz >= GX * GY);
  const bf16* __restrict__ Ahi  = sel ? a1.Ahi  : a0.Ahi;
  const bf16* __restrict__ Axhi = sel ? a1.Axhi : a0.Axhi;
  const bf16* __restrict__ Whi  = sel ? a1.Whi  : a0.Whi;
  const float* __restrict__ bsum = sel ? a1.bsum : a0.bsum;
  const float* __restrict__ wihp = sel ? a1.wihp : a0.wihp;
  const float* __restrict__ ytp  = sel ? a1.ytp  : a0.ytp;
  float* __restrict__ cst = sel ? a1.c   : a0.c;
  bf16*  __restrict__ Hhi = sel ? a1.Hhi : a0.Hhi;
  float* __restrict__ hf  = sel ? a1.hf  : a0.hf;
  const int hf_stride = sel ? a1.hf_stride : a0.hf_stride;
  const int ytstride  = sel ? a1.ytstride  : a0.ytstride;

  const int rem = (ZD == 2) ? (swz & (GX * GY - 1)) : swz;
  const int nb = rem / GY;
  const int mb = rem % GY;
  const int m0 = mb * BMT, n0 = nb * BNP;

  const int lane = tid & 63;
  const int wv = tid >> 6;            // 0..3

  // ---- inverse-swizzle decode: LDS chunk q -> source (row, col) ----
  // forward write swizzle was chunk = (ra*4+kc) ^ (ra&7) (+256 for rows>=64)
  auto dec_q = [](int q, int& row, int& col) {
    const int hi = q >> 8;
    const int qp = q & 255;
    const int c2 = ((qp >> 2) ^ (qp >> 4)) & 1;
    const int c1 = ((qp >> 1) ^ (qp >> 3)) & 1;
    const int c0 = (qp ^ c2) & 1;
    const int c = (qp & 0xF8) | (c2 << 2) | (c1 << 1) | c0;
    row = hi * 64 + (c >> 2);
    col = (c & 3) * 8;
  };
  int r0, c0, r1, c1;
  dec_q(wv * 64 + lane, r0, c0);        // span wv
  dec_q((wv + 4) * 64 + lane, r1, c1);  // span wv+4
  const int ldsS0 = wv * 512;           // span base, elements
  const int ldsS1 = (wv + 4) * 512;

  // async global->LDS staging: 4 DMA issues/thread/kt, LDS dest linear,
  // source pre-swizzled. No staging VGPRs, no ds_writes.
  auto issue_tile = [&](int kt, int p) {
    const int kb = kt * 32;
    const bf16 *a0p, *a1p;
    if (!HAS_X || kb < HG) {
      a0p = Ahi + (size_t)(m0 + r0) * HG + kb + c0;
      a1p = Ahi + (size_t)(m0 + r1) * HG + kb + c1;
    } else {
      a0p = Axhi + (size_t)(m0 + r0) * 32 + (kb - HG) + c0;
      a1p = Axhi + (size_t)(m0 + r1) * 32 + (kb - HG) + c1;
    }
    const bf16* b0p = Whi + (size_t)(n0 + r0) * KPAD + kb + c0;
    const bf16* b1p = Whi + (size_t)(n0 + r1) * KPAD + kb + c1;
    __builtin_amdgcn_global_load_lds((AS1C)a0p, (AS3P)&As[p][ldsS0], 16, 0, 0);
    __builtin_amdgcn_global_load_lds((AS1C)a1p, (AS3P)&As[p][ldsS1], 16, 0, 0);
    __builtin_amdgcn_global_load_lds((AS1C)b0p, (AS3P)&Bh[p][ldsS0], 16, 0, 0);
    __builtin_amdgcn_global_load_lds((AS1C)b1p, (AS3P)&Bh[p][ldsS1], 16, 0, 0);
  };

  const int wr = (wv >> 1), wc = wv & 1;  // 2x2 wave grid: 64x64 each
  const int l15 = lane & 15;
  const int lk = (lane >> 4) * 8;

  // XOR-swizzled read offsets (unchanged from R13); +16 rows = +512 elems
  const int rswz = (l15 & 7) << 3;
  const int aoff0 = (((wr * 64 + l15) * 32) + lk) ^ rswz;
  const int boff0 = (((wc * 64 + l15) * 32) + lk) ^ rswz;

  f32x4 acc[4][4] = {};

  issue_tile(0, 0);
  for (int kt = 0; kt < KT; ++kt) {
    __syncthreads();  // compiler vmcnt(0) drain: tile kt resident; prior
                      // reads of buf[p^1] retired before next DMA lands
    const int p = kt & 1;
    if (kt + 1 < KT) issue_tile(kt + 1, p ^ 1);

    bf16x8 ah[4];
#pragma unroll
    for (int mi = 0; mi < 4; ++mi)
      ah[mi] = __builtin_bit_cast(bf16x8,
                 *reinterpret_cast<const uint4*>(&As[p][aoff0 + mi * 512]));
#pragma unroll
    for (int ni = 0; ni < 4; ++ni) {
      bf16x8 bhv = __builtin_bit_cast(bf16x8,
                     *reinterpret_cast<const uint4*>(&Bh[p][boff0 + ni * 512]));
#pragma unroll
      for (int mi = 0; mi < 4; ++mi)
        acc[mi][ni] = __builtin_amdgcn_mfma_f32_16x16x32_bf16(ah[mi], bhv, acc[mi][ni], 0, 0, 0);
    }
  }

  // Epilogue: ni == gate g; j = nb*32 + wc*16 + l15
  const int j = nb * 32 + wc * 16 + l15;
  const int npb = nb * 128 + wc * 64 + l15;
  const float bs0 = bsum[npb], bs1 = bsum[npb + 16];
  const float bs2 = bsum[npb + 32], bs3 = bsum[npb + 48];
  float w0 = 0.f, w1 = 0.f, w2 = 0.f, w3 = 0.f;
  if (!HAS_X) {
    w0 = wihp[npb]; w1 = wihp[npb + 16];
    w2 = wihp[npb + 32]; w3 = wihp[npb + 48];
  }
#pragma unroll
  for (int mi = 0; mi < 4; ++mi) {
#pragma unroll
    for (int r = 0; r < 4; ++r) {
      const int rowl = wr * 64 + mi * 16 + (lane >> 4) * 4 + r;
      const size_t rowg = m0 + rowl;
      float gi = acc[mi][0][r] + bs0;
      float gf = acc[mi][1][r] + bs1;
      float gg = acc[mi][2][r] + bs2;
      float go = acc[mi][3][r] + bs3;
      if (!HAS_X) {
        const float yv = ytp[rowg * ytstride];
        gi += yv * w0; gf += yv * w1; gg += yv * w2; go += yv * w3;
      }
      const float i_ = 1.f / (1.f + __expf(-gi));
      const float f_ = 1.f / (1.f + __expf(-gf));
      const float tg = __expf(2.f * gg);
      const float g_ = (tg - 1.f) / (tg + 1.f);
      const float o_ = 1.f / (1.f + __expf(-go));
      const size_t idx = rowg * HG + j;
      const float cn = f_ * cst[idx] + i_ * g_;
      cst[idx] = cn;
      const float tc = __expf(2.f * cn);
      const float hn = o_ * (tc - 1.f) / (tc + 1.f);
      Hhi[idx] = __float2bfloat16(hn);
      if (hf) hf[rowg * hf_stride + j] = hn;
    }
  }
}

// All three weight rebuilds in ONE dispatch (block-range dispatch).
// Composite n'-interleaved order, hi only; bsum; wihp.
// set0: enc0 (544 blocks), set1: enc1 (544), set2: dec (2048).
__global__ void build_all_w_k(
    const float* __restrict__ W0hh, const float* __restrict__ W0ih,
    const float* __restrict__ b0ih, const float* __restrict__ b0hh,
    const float* __restrict__ W1hh, const float* __restrict__ W1ih,
    const float* __restrict__ b1ih, const float* __restrict__ b1hh,
    const float* __restrict__ Wdhh, const float* __restrict__ Wdih,
    const float* __restrict__ bdih, const float* __restrict__ bdhh,
    bf16* __restrict__ W0hi, bf16* __restrict__ W1hi, bf16* __restrict__ Wdhi,
    float* __restrict__ bs0, float* __restrict__ bs1,
    float* __restrict__ bsd, float* __restrict__ wihp) {
  const int bid = blockIdx.x;
  const float *Whh, *Wih, *bih, *bhh;
  bf16 *Whi;
  float *bsum, *wp;
  int HG, nx, Kpad, base;
  if (bid < 544) {
    Whh = W0hh; Wih = W0ih; bih = b0ih; bhh = b0hh;
    Whi = W0hi; bsum = bs0; wp = nullptr;
    HG = Hs; nx = 16; Kpad = 544; base = 0;
  } else if (bid < 1088) {
    Whh = W1hh; Wih = W1ih; bih = b1ih; bhh = b1hh;
    Whi = W1hi; bsum = bs1; wp = nullptr;
    HG = Hs; nx = 15; Kpad = 544; base = 544;
  } else {
    Whh = Wdhh; Wih = Wdih; bih = bdih; bhh = bdhh;
    Whi = Wdhi; bsum = bsd; wp = wihp;
    HG = 2 * Hs; nx = 0; Kpad = 1024; base = 1088;
  }
  const int chunks = Kpad >> 3;
  const int idx = (bid - base) * 256 + threadIdx.x;
  if (idx >= 4 * HG * chunks) return;
  const int np = idx / chunks;
  const int k0 = (idx - np * chunks) << 3;
  const int g = (np >> 4) & 3;
  const int jj = ((np >> 6) << 4) + (np & 15);
  const int norig = g * HG + jj;
  float v[8];
  if (k0 + 8 <= HG) {
    const float4* s = reinterpret_cast<const float4*>(Whh + (size_t)norig * HG + k0);
    float4 v0 = s[0], v1 = s[1];
    v[0] = v0.x; v[1] = v0.y; v[2] = v0.z; v[3] = v0.w;
    v[4] = v1.x; v[5] = v1.y; v[6] = v1.z; v[7] = v1.w;
  } else {
#pragma unroll
    for (int u = 0; u < 8; ++u) {
      const int k = k0 + u;
      v[u] = (k < HG) ? Whh[(size_t)norig * HG + k]
                      : ((k - HG < nx) ? Wih[(size_t)norig * nx + (k - HG)] : 0.f);
    }
  }
  unsigned short hh[8];
#pragma unroll
  for (int u = 0; u < 8; ++u) {
    const bf16 h = __float2bfloat16(v[u]);
    hh[u] = *reinterpret_cast<const unsigned short*>(&h);
  }
  const size_t off = (size_t)np * Kpad + k0;
  *reinterpret_cast<uint4*>((unsigned short*)Whi + off) = *reinterpret_cast<uint4*>(hh);
  if (k0 == 0) {
    bsum[np] = bih[norig] + bhh[norig];
    if (wp) wp[np] = Wih[norig];  // dec: Wih is (8H,1)
  }
}

// Per-batch encoder attention weights (time-invariant) -> x_tilde tables.
// Tables are stride-32 with cols 16..31 (and x2 col 15) prebuilt ZERO so the
// lstm kernel's DMA tail needs no predication.
__global__ void prep_attn_k(const float* __restrict__ X, const float* __restrict__ yp,
                            const float* __restrict__ encW, const float* __restrict__ encb,
                            bf16* __restrict__ x1h, bf16* __restrict__ x2h) {
  const int b = blockIdx.x;
  const int tid = threadIdx.x;  // 64
  __shared__ float wf[T1], ypb[T1];
  __shared__ float s1[16], s2[IN2], e1[16], e2[IN2];
  if (tid < T1) {
    wf[tid] = encW[2 * Hs + tid];
    ypb[tid] = yp[(size_t)b * T1 + tid];
  }
  __syncthreads();
  const float bb = encb[0];
  if (tid < 16) {
    float acc = bb;
    for (int t = 0; t < T1; ++t) {
      float xv = (tid < IN2) ? X[(size_t)b * (T1 * IN2) + t * IN2 + tid] : ypb[t];
      acc += xv * wf[t];
    }
    s1[tid] = acc;
  } else if (tid < 16 + IN2) {
    const int k = tid - 16;
    float acc = bb;
    for (int t = 0; t < T1; ++t)
      acc += X[(size_t)b * (T1 * IN2) + t * IN2 + k] * ypb[t] * wf[t];
    s2[k] = acc;
  }
  __syncthreads();
  if (tid < 16) {
    float m = -1e30f;
    for (int k = 0; k < 16; ++k) m = fmaxf(m, s1[k]);
    e1[tid] = expf(s1[tid] - m);
  } else if (tid < 16 + IN2) {
    const int k = tid - 16;
    float m = -1e30f;
    for (int kk = 0; kk < IN2; ++kk) m = fmaxf(m, s2[kk]);
    e2[k] = expf(s2[k] - m);
  }
  __syncthreads();
  if (tid < 16) {
    float sum = 0.f;
    for (int k = 0; k < 16; ++k) sum += e1[k];
    const float a = e1[tid] / sum;
    for (int t = 0; t < T1; ++t) {
      float xv = (tid < IN2) ? X[(size_t)b * (T1 * IN2) + t * IN2 + tid] : ypb[t];
      x1h[((size_t)t * Bsz + b) * 32 + tid] = __float2bfloat16(a * xv);
    }
  } else if (tid < 16 + IN2) {
    const int k = tid - 16;
    float sum = 0.f;
    for (int kk = 0; kk < IN2; ++kk) sum += e2[kk];
    const float a = e2[k] / sum;
    for (int t = 0; t < T1; ++t)
      x2h[((size_t)t * Bsz + b) * 32 + k] =
          __float2bfloat16(a * X[(size_t)b * (T1 * IN2) + t * IN2 + k] * ypb[t]);
  } else if (tid == 31) {
    const bf16 z = __float2bfloat16(0.f);
    for (int t = 0; t < T1; ++t) x2h[((size_t)t * Bsz + b) * 32 + 15] = z;
  } else if (tid >= 32 && tid < 48) {
    const int col = tid - 16;  // 16..31
    const bf16 z = __float2bfloat16(0.f);
    for (int t = 0; t < T1; ++t) {
      x1h[((size_t)t * Bsz + b) * 32 + col] = z;
      x2h[((size_t)t * Bsz + b) * 32 + col] = z;
    }
  }
}

// v[dd] = sum_h dec_attn2_W[0,h] * dec_attn1_W[h, 4H+dd]
// Wave-per-output GEMV: grid 1024 x 64 threads, lane l sums 8 h's, shfl-reduce.
__global__ void prep_v_k(const float* __restrict__ A1W, const float* __restrict__ A2W,
                         float* __restrict__ v) {
  const int dd = blockIdx.x;      // 0..1023
  const int l = threadIdx.x;      // 0..63
  float acc = 0.f;
#pragma unroll
  for (int k = 0; k < 8; ++k) {
    const int h = l + 64 * k;
    acc += A2W[h] * A1W[(size_t)h * (6 * Hs) + 4 * Hs + dd];
  }
#pragma unroll
  for (int off = 32; off > 0; off >>= 1) acc += __shfl_down(acc, off);
  if (l == 0) v[dd] = acc;
}

// Decoder attention (step-invariant): float4 + shuffle reductions; Xe tile
// cached in registers between the score and context passes.
__global__ void dec_ctx_k(const float* __restrict__ Xe, const float* __restrict__ v,
                          const float* __restrict__ yp, const float* __restrict__ fcW,
                          const float* __restrict__ fcb,
                          float* __restrict__ ctx, float* __restrict__ yt) {
  const int b = blockIdx.x;
  const int tid = threadIdx.x;  // 256
  const int lane = tid & 63, wid = tid >> 6;
  const float* xb = Xe + (size_t)b * (T1 * 2 * Hs);
  const int d0 = tid * 4;       // 256*4 = 1024 = 2*Hs
  const float4 v4 = *reinterpret_cast<const float4*>(v + d0);
  float4 x4[T1];
  float s[T1];
#pragma unroll
  for (int t = 0; t < T1; ++t) {
    x4[t] = *reinterpret_cast<const float4*>(xb + t * 2 * Hs + d0);
    s[t] = x4[t].x * v4.x + x4[t].y * v4.y + x4[t].z * v4.z + x4[t].w * v4.w;
  }
  __shared__ float part[T1][4];
  __shared__ float score[T1];
  __shared__ float tot2[4];
  __shared__ float cfs;
#pragma unroll
  for (int t = 0; t < T1; ++t) {
    float r = s[t];
#pragma unroll
    for (int off = 32; off > 0; off >>= 1) r += __shfl_down(r, off);
    if (lane == 0) part[t][wid] = r;
  }
  __syncthreads();
  if (tid < T1) score[tid] = part[tid][0] + part[tid][1] + part[tid][2] + part[tid][3];
  __syncthreads();
  float mx = -1e30f;
#pragma unroll
  for (int t = 0; t < T1; ++t) mx = fmaxf(mx, score[t]);
  float e[T1];
  float sum = 0.f;
#pragma unroll
  for (int t = 0; t < T1; ++t) { e[t] = expf(score[t] - mx); sum += e[t]; }
  const float inv = 1.f / sum;
  float4 c4 = {0.f, 0.f, 0.f, 0.f};
#pragma unroll
  for (int t = 0; t < T1; ++t) {
    c4.x += e[t] * x4[t].x; c4.y += e[t] * x4[t].y;
    c4.z += e[t] * x4[t].z; c4.w += e[t] * x4[t].w;
  }
  c4.x *= inv; c4.y *= inv; c4.z *= inv; c4.w *= inv;
  *reinterpret_cast<float4*>(ctx + (size_t)b * 2 * Hs + d0) = c4;
  const float4 f4 = *reinterpret_cast<const float4*>(fcW + d0);
  float fcacc = c4.x * f4.x + c4.y * f4.y + c4.z * f4.z + c4.w * f4.w;
#pragma unroll
  for (int off = 32; off > 0; off >>= 1) fcacc += __shfl_down(fcacc, off);
  if (lane == 0) tot2[wid] = fcacc;
  __syncthreads();
  if (tid == 0) cfs = tot2[0] + tot2[1] + tot2[2] + tot2[3] + fcb[0];
  __syncthreads();
  if (tid < T1) yt[(size_t)b * T1 + tid] = cfs + yp[(size_t)b * T1 + tid] * fcW[2 * Hs];
}

__global__ void final_out_k(const float* __restrict__ dfin, const float* __restrict__ ctx,
                            const float* __restrict__ Wfin, const float* __restrict__ bfin,
                            float* __restrict__ out) {
  const int b = blockIdx.x;
  const int tid = threadIdx.x;  // 256
  const int lane = tid & 63, wid = tid >> 6;
  const int d0 = tid * 4;
  const float4 a4 = *reinterpret_cast<const float4*>(dfin + (size_t)b * 2 * Hs + d0);
  const float4 w4 = *reinterpret_cast<const float4*>(Wfin + d0);
  const float4 c4 = *reinterpret_cast<const float4*>(ctx + (size_t)b * 2 * Hs + d0);
  const float4 u4 = *reinterpret_cast<const float4*>(Wfin + 2 * Hs + d0);
  float acc = a4.x * w4.x + a4.y * w4.y + a4.z * w4.z + a4.w * w4.w
            + c4.x * u4.x + c4.y * u4.y + c4.z * u4.z + c4.w * u4.w;
#pragma unroll
  for (int off = 32; off > 0; off >>= 1) acc += __shfl_down(acc, off);
  __shared__ float red[4];
  if (lane == 0) red[wid] = acc;
  __syncthreads();
  if (tid == 0) out[b] = red[0] + red[1] + red[2] + red[3] + bfin[0];
}

extern "C" void kernel_launch(void* const* d_in, const int* in_sizes, int n_in,
                              void* d_out, int out_size, void* d_ws, size_t ws_size,
                              hipStream_t stream) {
  const float* X     = (const float*)d_in[0];
  const float* yp    = (const float*)d_in[1];
  const float* encW  = (const float*)d_in[2];
  const float* encb  = (const float*)d_in[3];
  const float* e0Wih = (const float*)d_in[4];
  const float* e0Whh = (const float*)d_in[5];
  const float* e0bih = (const float*)d_in[6];
  const float* e0bhh = (const float*)d_in[7];
  const float* e1Wih = (const float*)d_in[8];
  const float* e1Whh = (const float*)d_in[9];
  const float* e1bih = (const float*)d_in[10];
  const float* e1bhh = (const float*)d_in[11];
  const float* dA1W  = (const float*)d_in[12];
  const float* dA2W  = (const float*)d_in[14];
  const float* dWih  = (const float*)d_in[16];
  const float* dWhh  = (const float*)d_in[17];
  const float* dbih  = (const float*)d_in[18];
  const float* dbhh  = (const float*)d_in[19];
  const float* fcW   = (const float*)d_in[20];
  const float* fcb   = (const float*)d_in[21];
  const float* WfinW = (const float*)d_in[22];
  const float* Wfinb = (const float*)d_in[23];
  float* out = (float*)d_out;
  (void)in_sizes; (void)n_in; (void)out_size; (void)ws_size;

  char* wsb = (char*)d_ws;
  size_t off = 0;
  auto alloc = [&](size_t bytes) -> void* {
    void* p = wsb + off;
    off = (off + bytes + 255) & ~(size_t)255;
    return p;
  };
  const size_t BH  = (size_t)Bsz * Hs;
  const size_t BH2 = (size_t)Bsz * 2 * Hs;
  // ---- zero-init region (one memset per call) ----
  float* c1   = (float*)alloc(BH * 4);
  float* c2   = (float*)alloc(BH * 4);
  float* cdec = (float*)alloc(BH2 * 4);
  bf16* h1hi0 = (bf16*)alloc(BH * 2);
  bf16* h2hi0 = (bf16*)alloc(BH * 2);
  bf16* dhi0  = (bf16*)alloc(BH2 * 2);
  const size_t zero_bytes = off;
  // ---- rest ----
  bf16* h1hi1 = (bf16*)alloc(BH * 2);
  bf16* h2hi1 = (bf16*)alloc(BH * 2);
  bf16* dhi1  = (bf16*)alloc(BH2 * 2);
  bf16* W0hi  = (bf16*)alloc((size_t)2048 * 544 * 2);
  bf16* W1hi  = (bf16*)alloc((size_t)2048 * 544 * 2);
  bf16* Wdhi  = (bf16*)alloc((size_t)4096 * 1024 * 2);
  float* bs0  = (float*)alloc(2048 * 4);
  float* bs1  = (float*)alloc(2048 * 4);
  float* bsd  = (float*)alloc(4096 * 4);
  float* wihp = (float*)alloc(4096 * 4);
  bf16* x1h   = (bf16*)alloc((size_t)T1 * Bsz * 32 * 2);
  bf16* x2h   = (bf16*)alloc((size_t)T1 * Bsz * 32 * 2);
  float* Xe   = (float*)alloc((size_t)Bsz * T1 * 2 * Hs * 4);
  float* dfp  = (float*)alloc(BH2 * 4);
  float* ctx  = (float*)alloc(BH2 * 4);
  float* vv   = (float*)alloc(2 * Hs * 4);
  float* yt   = (float*)alloc((size_t)Bsz * T1 * 4);

  hipMemsetAsync(d_ws, 0, zero_bytes, stream);

  build_all_w_k<<<3136, 256, 0, stream>>>(
      e0Whh, e0Wih, e0bih, e0bhh, e1Whh, e1Wih, e1bih, e1bhh,
      dWhh, dWih, dbih, dbhh,
      W0hi, W1hi, Wdhi, bs0, bs1, bsd, wihp);
  prep_attn_k<<<Bsz, 64, 0, stream>>>(X, yp, encW, encb, x1h, x2h);
  prep_v_k<<<2 * Hs, 64, 0, stream>>>(dA1W, dA2W, vv);

  // ---- encoder: 9 steps, both branches per launch ----
  bf16 *h1c = h1hi0, *h1n = h1hi1;
  bf16 *h2c = h2hi0, *h2n = h2hi1;
  for (int t = 0; t < T1; ++t) {
    GA a0{h1c, x1h + (size_t)t * Bsz * 32, W0hi, bs0, nullptr, nullptr,
          c1, h1n, Xe + (size_t)t * 2 * Hs, T1 * 2 * Hs, 0};
    GA a1{h2c, x2h + (size_t)t * Bsz * 32, W1hi, bs1, nullptr, nullptr,
          c2, h2n, Xe + (size_t)t * 2 * Hs + Hs, T1 * 2 * Hs, 0};
    dim3 grid((4 * Hs) / BNP, Bsz / BMT, 2);
    lstm2_k<Hs, 544, true, 2><<<grid, 256, 0, stream>>>(a0, a1);
    bf16* tp;
    tp = h1c; h1c = h1n; h1n = tp;
    tp = h2c; h2c = h2n; h2n = tp;
  }

  dec_ctx_k<<<Bsz, 256, 0, stream>>>(Xe, vv, yp, fcW, fcb, ctx, yt);

  // ---- decoder: 9 steps ----
  bf16 *dc = dhi0, *dn = dhi1;
  for (int t = 0; t < T1; ++t) {
    GA a0{dc, nullptr, Wdhi, bsd, wihp, yt + t,
          cdec, dn, (t == T1 - 1) ? dfp : nullptr, 2 * Hs, T1};
    dim3 grid((8 * Hs) / BNP, Bsz / BMT, 1);
    lstm2_k<2 * Hs, 1024, false, 1><<<grid, 256, 0, stream>>>(a0, a0);
    bf16* tp = dc; dc = dn; dn = tp;
  }

  final_out_k<<<Bsz, 256, 0, stream>>>(dfp, ctx, WfinW, Wfinb, out);
}

// Round 16
// 493.880 us; speedup vs baseline: 1.2440x; 1.0892x over previous
//
#include <hip/hip_runtime.h>
#include <hip/hip_bf16.h>
#include <math.h>

// Problem constants
#define Bsz 2048
#define T1  9      // T-1
#define Hs  512
#define IN2 15

typedef __bf16 bf16x8 __attribute__((ext_vector_type(8)));
typedef float  f32x4  __attribute__((ext_vector_type(4)));
typedef __hip_bfloat16 bf16;

#define AS1C const __attribute__((address_space(1))) void*
#define AS3P __attribute__((address_space(3))) void*

// ---------------------------------------------------------------------------
// Algebra (verified rounds 1-15):
//  * enc softmax over features invariant to (h@Wh+s@Ws) scalar => a1/a2
//    constant over time; Wh/Ws dead.
//  * dec attention: score = Xe.v + const(b), v = W2@W1x => beta/context
//    constant across decoder steps; rank-1 y_tilde term folded into epilogue.
//  * THIS ROUND (t=0 specialization, exact): h=c=0 at step 0 =>
//      - decoder t=0: gates = bsum + y_tilde*wihp (NO GEMM, epilogue only)
//      - encoder t=0: only the x K-tile contributes (KSTART=512, 1 tile)
//    and the h/c zero-init memset is dead (t=0 never reads them).
// Precision: bf16x1 (validated R13: absmax 0.00195, 3x margin).
// Schedule: R13/R15 structure (128x128, 4 waves, single-barrier dbuf,
// XOR swizzle, global_load_lds with pre-swizzled source). Six scheduling
// variants (R7/R10/R12/R14 regress; R11/R15 neutral) confirm local optimum
// at 2 blocks/CU (grid-limited by problem geometry).
// Weight layout n' = (j/16)*64 + g*16 + (j%16): a 64-wide wave n' window holds
// all 4 gates for 16 j's -> fully in-register gate epilogue.
// ---------------------------------------------------------------------------

#define BMT 128   // rows (batch) per block
#define BNP 128   // n' cols per block

struct GA {
  const bf16* Ahi;   // B x HG   activations (hi)
  const bf16* Axhi;  // B x 32   x-part for this t (enc, zero-padded) or null
  const bf16* Whi;   // 4HG x Kpad, n'-ordered
  const float* bsum; // 4HG, n'-ordered (bih+bhh)
  const float* wihp; // 4HG, n'-ordered rank-1 weights (dec) or null
  const float* ytp;  // rank-1 activation column y_tilde (dec) or null
  float* c;          // B x HG cell state (in/out; write-only when FIRST)
  bf16* Hhi;         // B x HG h out
  float* hf;         // optional fp32 h out (Xe slice / final d) or null
  int hf_stride;
  int ytstride;
};

template<int HG, int KPAD, bool HAS_X, int ZD, int KSTART, bool FIRST>
__global__ __launch_bounds__(256, 2)
void lstm2_k(GA a0, GA a1) {
  constexpr int KT  = KPAD / 32;
  constexpr int KT0 = KSTART / 32;
  constexpr int GX = (4 * HG) / BNP;
  constexpr int GY = Bsz / BMT;       // 16
  constexpr int NWG = GX * GY * ZD;
  constexpr int Q = NWG / 8;

  __shared__ __align__(16) unsigned short As[2][4096];
  __shared__ __align__(16) unsigned short Bh[2][4096];

  const int tid = threadIdx.x;
  // bijective XCD swizzle (NWG % 8 == 0); mb fastest -> consecutive blocks on
  // one XCD share one weight n-panel in that XCD's L2.
  const int orig = blockIdx.x + GX * (blockIdx.y + GY * blockIdx.z);
  const int swz = (orig & 7) * Q + (orig >> 3);
  // ---- SCALAR field selects (block-uniform -> SGPR cselect, no scratch) ----
  const bool sel = (ZD == 2) && (swz >= GX * GY);
  const bf16* __restrict__ Ahi  = sel ? a1.Ahi  : a0.Ahi;
  const bf16* __restrict__ Axhi = sel ? a1.Axhi : a0.Axhi;
  const bf16* __restrict__ Whi  = sel ? a1.Whi  : a0.Whi;
  const float* __restrict__ bsum = sel ? a1.bsum : a0.bsum;
  const float* __restrict__ wihp = sel ? a1.wihp : a0.wihp;
  const float* __restrict__ ytp  = sel ? a1.ytp  : a0.ytp;
  float* __restrict__ cst = sel ? a1.c   : a0.c;
  bf16*  __restrict__ Hhi = sel ? a1.Hhi : a0.Hhi;
  float* __restrict__ hf  = sel ? a1.hf  : a0.hf;
  const int hf_stride = sel ? a1.hf_stride : a0.hf_stride;
  const int ytstride  = sel ? a1.ytstride  : a0.ytstride;

  const int rem = (ZD == 2) ? (swz & (GX * GY - 1)) : swz;
  const int nb = rem / GY;
  const int mb = rem % GY;
  const int m0 = mb * BMT, n0 = nb * BNP;

  const int lane = tid & 63;
  const int wv = tid >> 6;            // 0..3

  // ---- inverse-swizzle decode: LDS chunk q -> source (row, col) ----
  // forward write swizzle was chunk = (ra*4+kc) ^ (ra&7) (+256 for rows>=64)
  auto dec_q = [](int q, int& row, int& col) {
    const int hi = q >> 8;
    const int qp = q & 255;
    const int c2 = ((qp >> 2) ^ (qp >> 4)) & 1;
    const int c1 = ((qp >> 1) ^ (qp >> 3)) & 1;
    const int c0 = (qp ^ c2) & 1;
    const int c = (qp & 0xF8) | (c2 << 2) | (c1 << 1) | c0;
    row = hi * 64 + (c >> 2);
    col = (c & 3) * 8;
  };
  int r0, c0, r1, c1;
  dec_q(wv * 64 + lane, r0, c0);        // span wv
  dec_q((wv + 4) * 64 + lane, r1, c1);  // span wv+4
  const int ldsS0 = wv * 512;           // span base, elements
  const int ldsS1 = (wv + 4) * 512;

  // async global->LDS staging: 4 DMA issues/thread/kt, LDS dest linear,
  // source pre-swizzled. No staging VGPRs, no ds_writes.
  auto issue_tile = [&](int kt, int p) {
    const int kb = kt * 32;
    const bf16 *a0p, *a1p;
    if (!HAS_X || kb < HG) {
      a0p = Ahi + (size_t)(m0 + r0) * HG + kb + c0;
      a1p = Ahi + (size_t)(m0 + r1) * HG + kb + c1;
    } else {
      a0p = Axhi + (size_t)(m0 + r0) * 32 + (kb - HG) + c0;
      a1p = Axhi + (size_t)(m0 + r1) * 32 + (kb - HG) + c1;
    }
    const bf16* b0p = Whi + (size_t)(n0 + r0) * KPAD + kb + c0;
    const bf16* b1p = Whi + (size_t)(n0 + r1) * KPAD + kb + c1;
    __builtin_amdgcn_global_load_lds((AS1C)a0p, (AS3P)&As[p][ldsS0], 16, 0, 0);
    __builtin_amdgcn_global_load_lds((AS1C)a1p, (AS3P)&As[p][ldsS1], 16, 0, 0);
    __builtin_amdgcn_global_load_lds((AS1C)b0p, (AS3P)&Bh[p][ldsS0], 16, 0, 0);
    __builtin_amdgcn_global_load_lds((AS1C)b1p, (AS3P)&Bh[p][ldsS1], 16, 0, 0);
  };

  const int wr = (wv >> 1), wc = wv & 1;  // 2x2 wave grid: 64x64 each
  const int l15 = lane & 15;
  const int lk = (lane >> 4) * 8;

  // XOR-swizzled read offsets; +16 rows = +512 elems
  const int rswz = (l15 & 7) << 3;
  const int aoff0 = (((wr * 64 + l15) * 32) + lk) ^ rswz;
  const int boff0 = (((wc * 64 + l15) * 32) + lk) ^ rswz;

  f32x4 acc[4][4] = {};

  if constexpr (KT0 < KT) {
    issue_tile(KT0, 0);
    for (int kt = KT0; kt < KT; ++kt) {
      __syncthreads();  // compiler vmcnt(0) drain: tile kt resident; prior
                        // reads of buf[p^1] retired before next DMA lands
      const int p = (kt - KT0) & 1;
      if (kt + 1 < KT) issue_tile(kt + 1, p ^ 1);

      bf16x8 ah[4];
#pragma unroll
      for (int mi = 0; mi < 4; ++mi)
        ah[mi] = __builtin_bit_cast(bf16x8,
                   *reinterpret_cast<const uint4*>(&As[p][aoff0 + mi * 512]));
#pragma unroll
      for (int ni = 0; ni < 4; ++ni) {
        bf16x8 bhv = __builtin_bit_cast(bf16x8,
                       *reinterpret_cast<const uint4*>(&Bh[p][boff0 + ni * 512]));
#pragma unroll
        for (int mi = 0; mi < 4; ++mi)
          acc[mi][ni] = __builtin_amdgcn_mfma_f32_16x16x32_bf16(ah[mi], bhv, acc[mi][ni], 0, 0, 0);
      }
    }
  }

  // Epilogue: ni == gate g; j = nb*32 + wc*16 + l15
  const int j = nb * 32 + wc * 16 + l15;
  const int npb = nb * 128 + wc * 64 + l15;
  const float bs0 = bsum[npb], bs1 = bsum[npb + 16];
  const float bs2 = bsum[npb + 32], bs3 = bsum[npb + 48];
  float w0 = 0.f, w1 = 0.f, w2 = 0.f, w3 = 0.f;
  if (!HAS_X) {
    w0 = wihp[npb]; w1 = wihp[npb + 16];
    w2 = wihp[npb + 32]; w3 = wihp[npb + 48];
  }
#pragma unroll
  for (int mi = 0; mi < 4; ++mi) {
#pragma unroll
    for (int r = 0; r < 4; ++r) {
      const int rowl = wr * 64 + mi * 16 + (lane >> 4) * 4 + r;
      const size_t rowg = m0 + rowl;
      float gi = acc[mi][0][r] + bs0;
      float gf = acc[mi][1][r] + bs1;
      float gg = acc[mi][2][r] + bs2;
      float go = acc[mi][3][r] + bs3;
      if (!HAS_X) {
        const float yv = ytp[rowg * ytstride];
        gi += yv * w0; gf += yv * w1; gg += yv * w2; go += yv * w3;
      }
      const float i_ = 1.f / (1.f + __expf(-gi));
      const float f_ = 1.f / (1.f + __expf(-gf));
      const float tg = __expf(2.f * gg);
      const float g_ = (tg - 1.f) / (tg + 1.f);
      const float o_ = 1.f / (1.f + __expf(-go));
      const size_t idx = rowg * HG + j;
      float cn;
      if constexpr (FIRST) {
        cn = i_ * g_;                  // c=0 at t=0: no read
      } else {
        cn = f_ * cst[idx] + i_ * g_;
      }
      cst[idx] = cn;
      const float tc = __expf(2.f * cn);
      const float hn = o_ * (tc - 1.f) / (tc + 1.f);
      Hhi[idx] = __float2bfloat16(hn);
      if (hf) hf[rowg * hf_stride + j] = hn;
    }
  }
}

// All three weight rebuilds in ONE dispatch (block-range dispatch).
// Composite n'-interleaved order, hi only; bsum; wihp.
// set0: enc0 (544 blocks), set1: enc1 (544), set2: dec (2048).
__global__ void build_all_w_k(
    const float* __restrict__ W0hh, const float* __restrict__ W0ih,
    const float* __restrict__ b0ih, const float* __restrict__ b0hh,
    const float* __restrict__ W1hh, const float* __restrict__ W1ih,
    const float* __restrict__ b1ih, const float* __restrict__ b1hh,
    const float* __restrict__ Wdhh, const float* __restrict__ Wdih,
    const float* __restrict__ bdih, const float* __restrict__ bdhh,
    bf16* __restrict__ W0hi, bf16* __restrict__ W1hi, bf16* __restrict__ Wdhi,
    float* __restrict__ bs0, float* __restrict__ bs1,
    float* __restrict__ bsd, float* __restrict__ wihp) {
  const int bid = blockIdx.x;
  const float *Whh, *Wih, *bih, *bhh;
  bf16 *Whi;
  float *bsum, *wp;
  int HG, nx, Kpad, base;
  if (bid < 544) {
    Whh = W0hh; Wih = W0ih; bih = b0ih; bhh = b0hh;
    Whi = W0hi; bsum = bs0; wp = nullptr;
    HG = Hs; nx = 16; Kpad = 544; base = 0;
  } else if (bid < 1088) {
    Whh = W1hh; Wih = W1ih; bih = b1ih; bhh = b1hh;
    Whi = W1hi; bsum = bs1; wp = nullptr;
    HG = Hs; nx = 15; Kpad = 544; base = 544;
  } else {
    Whh = Wdhh; Wih = Wdih; bih = bdih; bhh = bdhh;
    Whi = Wdhi; bsum = bsd; wp = wihp;
    HG = 2 * Hs; nx = 0; Kpad = 1024; base = 1088;
  }
  const int chunks = Kpad >> 3;
  const int idx = (bid - base) * 256 + threadIdx.x;
  if (idx >= 4 * HG * chunks) return;
  const int np = idx / chunks;
  const int k0 = (idx - np * chunks) << 3;
  const int g = (np >> 4) & 3;
  const int jj = ((np >> 6) << 4) + (np & 15);
  const int norig = g * HG + jj;
  float v[8];
  if (k0 + 8 <= HG) {
    const float4* s = reinterpret_cast<const float4*>(Whh + (size_t)norig * HG + k0);
    float4 v0 = s[0], v1 = s[1];
    v[0] = v0.x; v[1] = v0.y; v[2] = v0.z; v[3] = v0.w;
    v[4] = v1.x; v[5] = v1.y; v[6] = v1.z; v[7] = v1.w;
  } else {
#pragma unroll
    for (int u = 0; u < 8; ++u) {
      const int k = k0 + u;
      v[u] = (k < HG) ? Whh[(size_t)norig * HG + k]
                      : ((k - HG < nx) ? Wih[(size_t)norig * nx + (k - HG)] : 0.f);
    }
  }
  unsigned short hh[8];
#pragma unroll
  for (int u = 0; u < 8; ++u) {
    const bf16 h = __float2bfloat16(v[u]);
    hh[u] = *reinterpret_cast<const unsigned short*>(&h);
  }
  const size_t off = (size_t)np * Kpad + k0;
  *reinterpret_cast<uint4*>((unsigned short*)Whi + off) = *reinterpret_cast<uint4*>(hh);
  if (k0 == 0) {
    bsum[np] = bih[norig] + bhh[norig];
    if (wp) wp[np] = Wih[norig];  // dec: Wih is (8H,1)
  }
}

// Per-batch encoder attention weights (time-invariant) -> x_tilde tables.
// Tables are stride-32 with cols 16..31 (and x2 col 15) prebuilt ZERO so the
// lstm kernel's DMA tail needs no predication.
__global__ void prep_attn_k(const float* __restrict__ X, const float* __restrict__ yp,
                            const float* __restrict__ encW, const float* __restrict__ encb,
                            bf16* __restrict__ x1h, bf16* __restrict__ x2h) {
  const int b = blockIdx.x;
  const int tid = threadIdx.x;  // 64
  __shared__ float wf[T1], ypb[T1];
  __shared__ float s1[16], s2[IN2], e1[16], e2[IN2];
  if (tid < T1) {
    wf[tid] = encW[2 * Hs + tid];
    ypb[tid] = yp[(size_t)b * T1 + tid];
  }
  __syncthreads();
  const float bb = encb[0];
  if (tid < 16) {
    float acc = bb;
    for (int t = 0; t < T1; ++t) {
      float xv = (tid < IN2) ? X[(size_t)b * (T1 * IN2) + t * IN2 + tid] : ypb[t];
      acc += xv * wf[t];
    }
    s1[tid] = acc;
  } else if (tid < 16 + IN2) {
    const int k = tid - 16;
    float acc = bb;
    for (int t = 0; t < T1; ++t)
      acc += X[(size_t)b * (T1 * IN2) + t * IN2 + k] * ypb[t] * wf[t];
    s2[k] = acc;
  }
  __syncthreads();
  if (tid < 16) {
    float m = -1e30f;
    for (int k = 0; k < 16; ++k) m = fmaxf(m, s1[k]);
    e1[tid] = expf(s1[tid] - m);
  } else if (tid < 16 + IN2) {
    const int k = tid - 16;
    float m = -1e30f;
    for (int kk = 0; kk < IN2; ++kk) m = fmaxf(m, s2[kk]);
    e2[k] = expf(s2[k] - m);
  }
  __syncthreads();
  if (tid < 16) {
    float sum = 0.f;
    for (int k = 0; k < 16; ++k) sum += e1[k];
    const float a = e1[tid] / sum;
    for (int t = 0; t < T1; ++t) {
      float xv = (tid < IN2) ? X[(size_t)b * (T1 * IN2) + t * IN2 + tid] : ypb[t];
      x1h[((size_t)t * Bsz + b) * 32 + tid] = __float2bfloat16(a * xv);
    }
  } else if (tid < 16 + IN2) {
    const int k = tid - 16;
    float sum = 0.f;
    for (int kk = 0; kk < IN2; ++kk) sum += e2[kk];
    const float a = e2[k] / sum;
    for (int t = 0; t < T1; ++t)
      x2h[((size_t)t * Bsz + b) * 32 + k] =
          __float2bfloat16(a * X[(size_t)b * (T1 * IN2) + t * IN2 + k] * ypb[t]);
  } else if (tid == 31) {
    const bf16 z = __float2bfloat16(0.f);
    for (int t = 0; t < T1; ++t) x2h[((size_t)t * Bsz + b) * 32 + 15] = z;
  } else if (tid >= 32 && tid < 48) {
    const int col = tid - 16;  // 16..31
    const bf16 z = __float2bfloat16(0.f);
    for (int t = 0; t < T1; ++t) {
      x1h[((size_t)t * Bsz + b) * 32 + col] = z;
      x2h[((size_t)t * Bsz + b) * 32 + col] = z;
    }
  }
}

// v[dd] = sum_h dec_attn2_W[0,h] * dec_attn1_W[h, 4H+dd]
// Wave-per-output GEMV: grid 1024 x 64 threads, lane l sums 8 h's, shfl-reduce.
__global__ void prep_v_k(const float* __restrict__ A1W, const float* __restrict__ A2W,
                         float* __restrict__ v) {
  const int dd = blockIdx.x;      // 0..1023
  const int l = threadIdx.x;      // 0..63
  float acc = 0.f;
#pragma unroll
  for (int k = 0; k < 8; ++k) {
    const int h = l + 64 * k;
    acc += A2W[h] * A1W[(size_t)h * (6 * Hs) + 4 * Hs + dd];
  }
#pragma unroll
  for (int off = 32; off > 0; off >>= 1) acc += __shfl_down(acc, off);
  if (l == 0) v[dd] = acc;
}

// Decoder attention (step-invariant): float4 + shuffle reductions; Xe tile
// cached in registers between the score and context passes.
__global__ void dec_ctx_k(const float* __restrict__ Xe, const float* __restrict__ v,
                          const float* __restrict__ yp, const float* __restrict__ fcW,
                          const float* __restrict__ fcb,
                          float* __restrict__ ctx, float* __restrict__ yt) {
  const int b = blockIdx.x;
  const int tid = threadIdx.x;  // 256
  const int lane = tid & 63, wid = tid >> 6;
  const float* xb = Xe + (size_t)b * (T1 * 2 * Hs);
  const int d0 = tid * 4;       // 256*4 = 1024 = 2*Hs
  const float4 v4 = *reinterpret_cast<const float4*>(v + d0);
  float4 x4[T1];
  float s[T1];
#pragma unroll
  for (int t = 0; t < T1; ++t) {
    x4[t] = *reinterpret_cast<const float4*>(xb + t * 2 * Hs + d0);
    s[t] = x4[t].x * v4.x + x4[t].y * v4.y + x4[t].z * v4.z + x4[t].w * v4.w;
  }
  __shared__ float part[T1][4];
  __shared__ float score[T1];
  __shared__ float tot2[4];
  __shared__ float cfs;
#pragma unroll
  for (int t = 0; t < T1; ++t) {
    float r = s[t];
#pragma unroll
    for (int off = 32; off > 0; off >>= 1) r += __shfl_down(r, off);
    if (lane == 0) part[t][wid] = r;
  }
  __syncthreads();
  if (tid < T1) score[tid] = part[tid][0] + part[tid][1] + part[tid][2] + part[tid][3];
  __syncthreads();
  float mx = -1e30f;
#pragma unroll
  for (int t = 0; t < T1; ++t) mx = fmaxf(mx, score[t]);
  float e[T1];
  float sum = 0.f;
#pragma unroll
  for (int t = 0; t < T1; ++t) { e[t] = expf(score[t] - mx); sum += e[t]; }
  const float inv = 1.f / sum;
  float4 c4 = {0.f, 0.f, 0.f, 0.f};
#pragma unroll
  for (int t = 0; t < T1; ++t) {
    c4.x += e[t] * x4[t].x; c4.y += e[t] * x4[t].y;
    c4.z += e[t] * x4[t].z; c4.w += e[t] * x4[t].w;
  }
  c4.x *= inv; c4.y *= inv; c4.z *= inv; c4.w *= inv;
  *reinterpret_cast<float4*>(ctx + (size_t)b * 2 * Hs + d0) = c4;
  const float4 f4 = *reinterpret_cast<const float4*>(fcW + d0);
  float fcacc = c4.x * f4.x + c4.y * f4.y + c4.z * f4.z + c4.w * f4.w;
#pragma unroll
  for (int off = 32; off > 0; off >>= 1) fcacc += __shfl_down(fcacc, off);
  if (lane == 0) tot2[wid] = fcacc;
  __syncthreads();
  if (tid == 0) cfs = tot2[0] + tot2[1] + tot2[2] + tot2[3] + fcb[0];
  __syncthreads();
  if (tid < T1) yt[(size_t)b * T1 + tid] = cfs + yp[(size_t)b * T1 + tid] * fcW[2 * Hs];
}

__global__ void final_out_k(const float* __restrict__ dfin, const float* __restrict__ ctx,
                            const float* __restrict__ Wfin, const float* __restrict__ bfin,
                            float* __restrict__ out) {
  const int b = blockIdx.x;
  const int tid = threadIdx.x;  // 256
  const int lane = tid & 63, wid = tid >> 6;
  const int d0 = tid * 4;
  const float4 a4 = *reinterpret_cast<const float4*>(dfin + (size_t)b * 2 * Hs + d0);
  const float4 w4 = *reinterpret_cast<const float4*>(Wfin + d0);
  const float4 c4 = *reinterpret_cast<const float4*>(ctx + (size_t)b * 2 * Hs + d0);
  const float4 u4 = *reinterpret_cast<const float4*>(Wfin + 2 * Hs + d0);
  float acc = a4.x * w4.x + a4.y * w4.y + a4.z * w4.z + a4.w * w4.w
            + c4.x * u4.x + c4.y * u4.y + c4.z * u4.z + c4.w * u4.w;
#pragma unroll
  for (int off = 32; off > 0; off >>= 1) acc += __shfl_down(acc, off);
  __shared__ float red[4];
  if (lane == 0) red[wid] = acc;
  __syncthreads();
  if (tid == 0) out[b] = red[0] + red[1] + red[2] + red[3] + bfin[0];
}

extern "C" void kernel_launch(void* const* d_in, const int* in_sizes, int n_in,
                              void* d_out, int out_size, void* d_ws, size_t ws_size,
                              hipStream_t stream) {
  const float* X     = (const float*)d_in[0];
  const float* yp    = (const float*)d_in[1];
  const float* encW  = (const float*)d_in[2];
  const float* encb  = (const float*)d_in[3];
  const float* e0Wih = (const float*)d_in[4];
  const float* e0Whh = (const float*)d_in[5];
  const float* e0bih = (const float*)d_in[6];
  const float* e0bhh = (const float*)d_in[7];
  const float* e1Wih = (const float*)d_in[8];
  const float* e1Whh = (const float*)d_in[9];
  const float* e1bih = (const float*)d_in[10];
  const float* e1bhh = (const float*)d_in[11];
  const float* dA1W  = (const float*)d_in[12];
  const float* dA2W  = (const float*)d_in[14];
  const float* dWih  = (const float*)d_in[16];
  const float* dWhh  = (const float*)d_in[17];
  const float* dbih  = (const float*)d_in[18];
  const float* dbhh  = (const float*)d_in[19];
  const float* fcW   = (const float*)d_in[20];
  const float* fcb   = (const float*)d_in[21];
  const float* WfinW = (const float*)d_in[22];
  const float* Wfinb = (const float*)d_in[23];
  float* out = (float*)d_out;
  (void)in_sizes; (void)n_in; (void)out_size; (void)ws_size;

  char* wsb = (char*)d_ws;
  size_t off = 0;
  auto alloc = [&](size_t bytes) -> void* {
    void* p = wsb + off;
    off = (off + bytes + 255) & ~(size_t)255;
    return p;
  };
  const size_t BH  = (size_t)Bsz * Hs;
  const size_t BH2 = (size_t)Bsz * 2 * Hs;
  // No memset needed: FIRST-step kernels never read h/c (write-only at t=0).
  float* c1   = (float*)alloc(BH * 4);
  float* c2   = (float*)alloc(BH * 4);
  float* cdec = (float*)alloc(BH2 * 4);
  bf16* h1hi0 = (bf16*)alloc(BH * 2);
  bf16* h2hi0 = (bf16*)alloc(BH * 2);
  bf16* dhi0  = (bf16*)alloc(BH2 * 2);
  bf16* h1hi1 = (bf16*)alloc(BH * 2);
  bf16* h2hi1 = (bf16*)alloc(BH * 2);
  bf16* dhi1  = (bf16*)alloc(BH2 * 2);
  bf16* W0hi  = (bf16*)alloc((size_t)2048 * 544 * 2);
  bf16* W1hi  = (bf16*)alloc((size_t)2048 * 544 * 2);
  bf16* Wdhi  = (bf16*)alloc((size_t)4096 * 1024 * 2);
  float* bs0  = (float*)alloc(2048 * 4);
  float* bs1  = (float*)alloc(2048 * 4);
  float* bsd  = (float*)alloc(4096 * 4);
  float* wihp = (float*)alloc(4096 * 4);
  bf16* x1h   = (bf16*)alloc((size_t)T1 * Bsz * 32 * 2);
  bf16* x2h   = (bf16*)alloc((size_t)T1 * Bsz * 32 * 2);
  float* Xe   = (float*)alloc((size_t)Bsz * T1 * 2 * Hs * 4);
  float* dfp  = (float*)alloc(BH2 * 4);
  float* ctx  = (float*)alloc(BH2 * 4);
  float* vv   = (float*)alloc(2 * Hs * 4);
  float* yt   = (float*)alloc((size_t)Bsz * T1 * 4);

  build_all_w_k<<<3136, 256, 0, stream>>>(
      e0Whh, e0Wih, e0bih, e0bhh, e1Whh, e1Wih, e1bih, e1bhh,
      dWhh, dWih, dbih, dbhh,
      W0hi, W1hi, Wdhi, bs0, bs1, bsd, wihp);
  prep_attn_k<<<Bsz, 64, 0, stream>>>(X, yp, encW, encb, x1h, x2h);
  prep_v_k<<<2 * Hs, 64, 0, stream>>>(dA1W, dA2W, vv);

  // ---- encoder: 9 steps, both branches per launch ----
  bf16 *h1c = h1hi0, *h1n = h1hi1;
  bf16 *h2c = h2hi0, *h2n = h2hi1;
  for (int t = 0; t < T1; ++t) {
    GA a0{h1c, x1h + (size_t)t * Bsz * 32, W0hi, bs0, nullptr, nullptr,
          c1, h1n, Xe + (size_t)t * 2 * Hs, T1 * 2 * Hs, 0};
    GA a1{h2c, x2h + (size_t)t * Bsz * 32, W1hi, bs1, nullptr, nullptr,
          c2, h2n, Xe + (size_t)t * 2 * Hs + Hs, T1 * 2 * Hs, 0};
    dim3 grid((4 * Hs) / BNP, Bsz / BMT, 2);
    if (t == 0)
      lstm2_k<Hs, 544, true, 2, 512, true><<<grid, 256, 0, stream>>>(a0, a1);
    else
      lstm2_k<Hs, 544, true, 2, 0, false><<<grid, 256, 0, stream>>>(a0, a1);
    bf16* tp;
    tp = h1c; h1c = h1n; h1n = tp;
    tp = h2c; h2c = h2n; h2n = tp;
  }

  dec_ctx_k<<<Bsz, 256, 0, stream>>>(Xe, vv, yp, fcW, fcb, ctx, yt);

  // ---- decoder: 9 steps ----
  bf16 *dc = dhi0, *dn = dhi1;
  for (int t = 0; t < T1; ++t) {
    GA a0{dc, nullptr, Wdhi, bsd, wihp, yt + t,
          cdec, dn, (t == T1 - 1) ? dfp : nullptr, 2 * Hs, T1};
    dim3 grid((8 * Hs) / BNP, Bsz / BMT, 1);
    if (t == 0)
      lstm2_k<2 * Hs, 1024, false, 1, 1024, true><<<grid, 256, 0, stream>>>(a0, a0);
    else
      lstm2_k<2 * Hs, 1024, false, 1, 0, false><<<grid, 256, 0, stream>>>(a0, a0);
    bf16* tp = dc; dc = dn; dn = tp;
  }

  final_out_k<<<Bsz, 256, 0, stream>>>(dfp, ctx, WfinW, Wfinb, out);
}

// Round 17
// 457.000 us; speedup vs baseline: 1.3444x; 1.0807x over previous
//
#include <hip/hip_runtime.h>
#include <hip/hip_bf16.h>
#include <math.h>

// Problem constants
#define Bsz 2048
#define T1  9      // T-1
#define Hs  512
#define IN2 15

typedef __bf16 bf16x8 __attribute__((ext_vector_type(8)));
typedef float  f32x4  __attribute__((ext_vector_type(4)));
typedef __hip_bfloat16 bf16;

#define AS1C const __attribute__((address_space(1))) void*
#define AS3P __attribute__((address_space(3))) void*

// ---------------------------------------------------------------------------
// Algebra (verified rounds 1-16):
//  * enc softmax over features invariant => a1/a2 constant over time.
//  * dec attention: beta/context constant across steps; rank-1 y_tilde term
//    in epilogue.  * t=0: dec = epilogue-only, enc = 1 K-tile; no h/c memset.
// Precision: bf16x1 (absmax 0.00195, 3x margin).
// R16 post-mortem: per-kt barrier drains expose DMA latency (compute phase
// ~250cy < DMA ~400-900cy). THIS ROUND: BK=64 — two K-tiles per LDS buffer
// phase. Per phase: 1 barrier, 8 DMAs, 32 MFMAs (~500+cy compute window) ->
// DMA latency covered, barrier count halved. LDS 64KB/block; still 2
// blocks/CU (grid-limited, so occupancy unchanged - m132 hazard n/a).
// Odd KT (enc 17 tiles): 8 pairs + single tail via in-loop guards.
// Weight layout n' = (j/16)*64 + g*16 + (j%16): a 64-wide wave n' window
// holds all 4 gates for 16 j's -> fully in-register gate epilogue.
// ---------------------------------------------------------------------------

#define BMT 128   // rows (batch) per block
#define BNP 128   // n' cols per block

struct GA {
  const bf16* Ahi;   // B x HG   activations (hi)
  const bf16* Axhi;  // B x 32   x-part for this t (enc, zero-padded) or null
  const bf16* Whi;   // 4HG x Kpad, n'-ordered
  const float* bsum; // 4HG, n'-ordered (bih+bhh)
  const float* wihp; // 4HG, n'-ordered rank-1 weights (dec) or null
  const float* ytp;  // rank-1 activation column y_tilde (dec) or null
  float* c;          // B x HG cell state (in/out; write-only when FIRST)
  bf16* Hhi;         // B x HG h out
  float* hf;         // optional fp32 h out (Xe slice / final d) or null
  int hf_stride;
  int ytstride;
};

template<int HG, int KPAD, bool HAS_X, int ZD, int KSTART, bool FIRST>
__global__ __launch_bounds__(256, 2)
void lstm2_k(GA a0, GA a1) {
  constexpr int KT  = KPAD / 32;
  constexpr int KT0 = KSTART / 32;
  constexpr int GX = (4 * HG) / BNP;
  constexpr int GY = Bsz / BMT;       // 16
  constexpr int NWG = GX * GY * ZD;
  constexpr int Q = NWG / 8;

  // two 32-K sub-tiles per buffer: [dbuf][subtile*4096 + swizzled chunk]
  __shared__ __align__(16) unsigned short As[2][8192];
  __shared__ __align__(16) unsigned short Bh[2][8192];

  const int tid = threadIdx.x;
  // bijective XCD swizzle (NWG % 8 == 0); mb fastest -> consecutive blocks on
  // one XCD share one weight n-panel in that XCD's L2.
  const int orig = blockIdx.x + GX * (blockIdx.y + GY * blockIdx.z);
  const int swz = (orig & 7) * Q + (orig >> 3);
  // ---- SCALAR field selects (block-uniform -> SGPR cselect, no scratch) ----
  const bool sel = (ZD == 2) && (swz >= GX * GY);
  const bf16* __restrict__ Ahi  = sel ? a1.Ahi  : a0.Ahi;
  const bf16* __restrict__ Axhi = sel ? a1.Axhi : a0.Axhi;
  const bf16* __restrict__ Whi  = sel ? a1.Whi  : a0.Whi;
  const float* __restrict__ bsum = sel ? a1.bsum : a0.bsum;
  const float* __restrict__ wihp = sel ? a1.wihp : a0.wihp;
  const float* __restrict__ ytp  = sel ? a1.ytp  : a0.ytp;
  float* __restrict__ cst = sel ? a1.c   : a0.c;
  bf16*  __restrict__ Hhi = sel ? a1.Hhi : a0.Hhi;
  float* __restrict__ hf  = sel ? a1.hf  : a0.hf;
  const int hf_stride = sel ? a1.hf_stride : a0.hf_stride;
  const int ytstride  = sel ? a1.ytstride  : a0.ytstride;

  const int rem = (ZD == 2) ? (swz & (GX * GY - 1)) : swz;
  const int nb = rem / GY;
  const int mb = rem % GY;
  const int m0 = mb * BMT, n0 = nb * BNP;

  const int lane = tid & 63;
  const int wv = tid >> 6;            // 0..3

  // ---- inverse-swizzle decode: LDS chunk q -> source (row, col) ----
  auto dec_q = [](int q, int& row, int& col) {
    const int hi = q >> 8;
    const int qp = q & 255;
    const int c2 = ((qp >> 2) ^ (qp >> 4)) & 1;
    const int c1 = ((qp >> 1) ^ (qp >> 3)) & 1;
    const int c0 = (qp ^ c2) & 1;
    const int c = (qp & 0xF8) | (c2 << 2) | (c1 << 1) | c0;
    row = hi * 64 + (c >> 2);
    col = (c & 3) * 8;
  };
  int r0, c0, r1, c1;
  dec_q(wv * 64 + lane, r0, c0);        // span wv
  dec_q((wv + 4) * 64 + lane, r1, c1);  // span wv+4
  const int ldsS0 = wv * 512;
  const int ldsS1 = (wv + 4) * 512;

  // async global->LDS staging of one 32-K tile into sub-slot s of buffer p
  auto issue_tile = [&](int kt, int p, int s) {
    const int kb = kt * 32;
    const int sb = s * 4096;
    const bf16 *a0p, *a1p;
    if (!HAS_X || kb < HG) {
      a0p = Ahi + (size_t)(m0 + r0) * HG + kb + c0;
      a1p = Ahi + (size_t)(m0 + r1) * HG + kb + c1;
    } else {
      a0p = Axhi + (size_t)(m0 + r0) * 32 + (kb - HG) + c0;
      a1p = Axhi + (size_t)(m0 + r1) * 32 + (kb - HG) + c1;
    }
    const bf16* b0p = Whi + (size_t)(n0 + r0) * KPAD + kb + c0;
    const bf16* b1p = Whi + (size_t)(n0 + r1) * KPAD + kb + c1;
    __builtin_amdgcn_global_load_lds((AS1C)a0p, (AS3P)&As[p][sb + ldsS0], 16, 0, 0);
    __builtin_amdgcn_global_load_lds((AS1C)a1p, (AS3P)&As[p][sb + ldsS1], 16, 0, 0);
    __builtin_amdgcn_global_load_lds((AS1C)b0p, (AS3P)&Bh[p][sb + ldsS0], 16, 0, 0);
    __builtin_amdgcn_global_load_lds((AS1C)b1p, (AS3P)&Bh[p][sb + ldsS1], 16, 0, 0);
  };

  const int wr = (wv >> 1), wc = wv & 1;  // 2x2 wave grid: 64x64 each
  const int l15 = lane & 15;
  const int lk = (lane >> 4) * 8;

  // XOR-swizzled read offsets within a 4096-elem sub-tile
  const int rswz = (l15 & 7) << 3;
  const int aoff0 = (((wr * 64 + l15) * 32) + lk) ^ rswz;
  const int boff0 = (((wc * 64 + l15) * 32) + lk) ^ rswz;

  f32x4 acc[4][4] = {};

  auto compute = [&](int p, int s) {
    const int sb = s * 4096;
    bf16x8 ah[4];
#pragma unroll
    for (int mi = 0; mi < 4; ++mi)
      ah[mi] = __builtin_bit_cast(bf16x8,
                 *reinterpret_cast<const uint4*>(&As[p][sb + aoff0 + mi * 512]));
#pragma unroll
    for (int ni = 0; ni < 4; ++ni) {
      bf16x8 bhv = __builtin_bit_cast(bf16x8,
                     *reinterpret_cast<const uint4*>(&Bh[p][sb + boff0 + ni * 512]));
#pragma unroll
      for (int mi = 0; mi < 4; ++mi)
        acc[mi][ni] = __builtin_amdgcn_mfma_f32_16x16x32_bf16(ah[mi], bhv, acc[mi][ni], 0, 0, 0);
    }
  };

  if constexpr (KT0 < KT) {
    // prologue: fill buffer 0 with up to two tiles
    issue_tile(KT0, 0, 0);
    if (KT0 + 1 < KT) issue_tile(KT0 + 1, 0, 1);
    int p = 0;
    for (int kt = KT0; kt < KT; kt += 2, p ^= 1) {
      __syncthreads();  // vmcnt(0) drain: buffer p resident; reads of p^1
                        // (previous phase) retired before its DMAs land
      if (kt + 2 < KT) {
        issue_tile(kt + 2, p ^ 1, 0);
        if (kt + 3 < KT) issue_tile(kt + 3, p ^ 1, 1);
      }
      compute(p, 0);
      if (kt + 1 < KT) compute(p, 1);
    }
  }

  // Epilogue: ni == gate g; j = nb*32 + wc*16 + l15
  const int j = nb * 32 + wc * 16 + l15;
  const int npb = nb * 128 + wc * 64 + l15;
  const float bs0 = bsum[npb], bs1 = bsum[npb + 16];
  const float bs2 = bsum[npb + 32], bs3 = bsum[npb + 48];
  float w0 = 0.f, w1 = 0.f, w2 = 0.f, w3 = 0.f;
  if (!HAS_X) {
    w0 = wihp[npb]; w1 = wihp[npb + 16];
    w2 = wihp[npb + 32]; w3 = wihp[npb + 48];
  }
#pragma unroll
  for (int mi = 0; mi < 4; ++mi) {
#pragma unroll
    for (int r = 0; r < 4; ++r) {
      const int rowl = wr * 64 + mi * 16 + (lane >> 4) * 4 + r;
      const size_t rowg = m0 + rowl;
      float gi = acc[mi][0][r] + bs0;
      float gf = acc[mi][1][r] + bs1;
      float gg = acc[mi][2][r] + bs2;
      float go = acc[mi][3][r] + bs3;
      if (!HAS_X) {
        const float yv = ytp[rowg * ytstride];
        gi += yv * w0; gf += yv * w1; gg += yv * w2; go += yv * w3;
      }
      const float i_ = 1.f / (1.f + __expf(-gi));
      const float f_ = 1.f / (1.f + __expf(-gf));
      const float tg = __expf(2.f * gg);
      const float g_ = (tg - 1.f) / (tg + 1.f);
      const float o_ = 1.f / (1.f + __expf(-go));
      const size_t idx = rowg * HG + j;
      float cn;
      if constexpr (FIRST) {
        cn = i_ * g_;                  // c=0 at t=0: no read
      } else {
        cn = f_ * cst[idx] + i_ * g_;
      }
      cst[idx] = cn;
      const float tc = __expf(2.f * cn);
      const float hn = o_ * (tc - 1.f) / (tc + 1.f);
      Hhi[idx] = __float2bfloat16(hn);
      if (hf) hf[rowg * hf_stride + j] = hn;
    }
  }
}

// All three weight rebuilds in ONE dispatch (block-range dispatch).
// Composite n'-interleaved order, hi only; bsum; wihp.
// set0: enc0 (544 blocks), set1: enc1 (544), set2: dec (2048).
__global__ void build_all_w_k(
    const float* __restrict__ W0hh, const float* __restrict__ W0ih,
    const float* __restrict__ b0ih, const float* __restrict__ b0hh,
    const float* __restrict__ W1hh, const float* __restrict__ W1ih,
    const float* __restrict__ b1ih, const float* __restrict__ b1hh,
    const float* __restrict__ Wdhh, const float* __restrict__ Wdih,
    const float* __restrict__ bdih, const float* __restrict__ bdhh,
    bf16* __restrict__ W0hi, bf16* __restrict__ W1hi, bf16* __restrict__ Wdhi,
    float* __restrict__ bs0, float* __restrict__ bs1,
    float* __restrict__ bsd, float* __restrict__ wihp) {
  const int bid = blockIdx.x;
  const float *Whh, *Wih, *bih, *bhh;
  bf16 *Whi;
  float *bsum, *wp;
  int HG, nx, Kpad, base;
  if (bid < 544) {
    Whh = W0hh; Wih = W0ih; bih = b0ih; bhh = b0hh;
    Whi = W0hi; bsum = bs0; wp = nullptr;
    HG = Hs; nx = 16; Kpad = 544; base = 0;
  } else if (bid < 1088) {
    Whh = W1hh; Wih = W1ih; bih = b1ih; bhh = b1hh;
    Whi = W1hi; bsum = bs1; wp = nullptr;
    HG = Hs; nx = 15; Kpad = 544; base = 544;
  } else {
    Whh = Wdhh; Wih = Wdih; bih = bdih; bhh = bdhh;
    Whi = Wdhi; bsum = bsd; wp = wihp;
    HG = 2 * Hs; nx = 0; Kpad = 1024; base = 1088;
  }
  const int chunks = Kpad >> 3;
  const int idx = (bid - base) * 256 + threadIdx.x;
  if (idx >= 4 * HG * chunks) return;
  const int np = idx / chunks;
  const int k0 = (idx - np * chunks) << 3;
  const int g = (np >> 4) & 3;
  const int jj = ((np >> 6) << 4) + (np & 15);
  const int norig = g * HG + jj;
  float v[8];
  if (k0 + 8 <= HG) {
    const float4* s = reinterpret_cast<const float4*>(Whh + (size_t)norig * HG + k0);
    float4 v0 = s[0], v1 = s[1];
    v[0] = v0.x; v[1] = v0.y; v[2] = v0.z; v[3] = v0.w;
    v[4] = v1.x; v[5] = v1.y; v[6] = v1.z; v[7] = v1.w;
  } else {
#pragma unroll
    for (int u = 0; u < 8; ++u) {
      const int k = k0 + u;
      v[u] = (k < HG) ? Whh[(size_t)norig * HG + k]
                      : ((k - HG < nx) ? Wih[(size_t)norig * nx + (k - HG)] : 0.f);
    }
  }
  unsigned short hh[8];
#pragma unroll
  for (int u = 0; u < 8; ++u) {
    const bf16 h = __float2bfloat16(v[u]);
    hh[u] = *reinterpret_cast<const unsigned short*>(&h);
  }
  const size_t off = (size_t)np * Kpad + k0;
  *reinterpret_cast<uint4*>((unsigned short*)Whi + off) = *reinterpret_cast<uint4*>(hh);
  if (k0 == 0) {
    bsum[np] = bih[norig] + bhh[norig];
    if (wp) wp[np] = Wih[norig];  // dec: Wih is (8H,1)
  }
}

// Per-batch encoder attention weights (time-invariant) -> x_tilde tables.
// Tables are stride-32 with cols 16..31 (and x2 col 15) prebuilt ZERO so the
// lstm kernel's DMA tail needs no predication.
__global__ void prep_attn_k(const float* __restrict__ X, const float* __restrict__ yp,
                            const float* __restrict__ encW, const float* __restrict__ encb,
                            bf16* __restrict__ x1h, bf16* __restrict__ x2h) {
  const int b = blockIdx.x;
  const int tid = threadIdx.x;  // 64
  __shared__ float wf[T1], ypb[T1];
  __shared__ float s1[16], s2[IN2], e1[16], e2[IN2];
  if (tid < T1) {
    wf[tid] = encW[2 * Hs + tid];
    ypb[tid] = yp[(size_t)b * T1 + tid];
  }
  __syncthreads();
  const float bb = encb[0];
  if (tid < 16) {
    float acc = bb;
    for (int t = 0; t < T1; ++t) {
      float xv = (tid < IN2) ? X[(size_t)b * (T1 * IN2) + t * IN2 + tid] : ypb[t];
      acc += xv * wf[t];
    }
    s1[tid] = acc;
  } else if (tid < 16 + IN2) {
    const int k = tid - 16;
    float acc = bb;
    for (int t = 0; t < T1; ++t)
      acc += X[(size_t)b * (T1 * IN2) + t * IN2 + k] * ypb[t] * wf[t];
    s2[k] = acc;
  }
  __syncthreads();
  if (tid < 16) {
    float m = -1e30f;
    for (int k = 0; k < 16; ++k) m = fmaxf(m, s1[k]);
    e1[tid] = expf(s1[tid] - m);
  } else if (tid < 16 + IN2) {
    const int k = tid - 16;
    float m = -1e30f;
    for (int kk = 0; kk < IN2; ++kk) m = fmaxf(m, s2[kk]);
    e2[k] = expf(s2[k] - m);
  }
  __syncthreads();
  if (tid < 16) {
    float sum = 0.f;
    for (int k = 0; k < 16; ++k) sum += e1[k];
    const float a = e1[tid] / sum;
    for (int t = 0; t < T1; ++t) {
      float xv = (tid < IN2) ? X[(size_t)b * (T1 * IN2) + t * IN2 + tid] : ypb[t];
      x1h[((size_t)t * Bsz + b) * 32 + tid] = __float2bfloat16(a * xv);
    }
  } else if (tid < 16 + IN2) {
    const int k = tid - 16;
    float sum = 0.f;
    for (int kk = 0; kk < IN2; ++kk) sum += e2[kk];
    const float a = e2[k] / sum;
    for (int t = 0; t < T1; ++t)
      x2h[((size_t)t * Bsz + b) * 32 + k] =
          __float2bfloat16(a * X[(size_t)b * (T1 * IN2) + t * IN2 + k] * ypb[t]);
  } else if (tid == 31) {
    const bf16 z = __float2bfloat16(0.f);
    for (int t = 0; t < T1; ++t) x2h[((size_t)t * Bsz + b) * 32 + 15] = z;
  } else if (tid >= 32 && tid < 48) {
    const int col = tid - 16;  // 16..31
    const bf16 z = __float2bfloat16(0.f);
    for (int t = 0; t < T1; ++t) {
      x1h[((size_t)t * Bsz + b) * 32 + col] = z;
      x2h[((size_t)t * Bsz + b) * 32 + col] = z;
    }
  }
}

// v[dd] = sum_h dec_attn2_W[0,h] * dec_attn1_W[h, 4H+dd]
// Wave-per-output GEMV: grid 1024 x 64 threads, lane l sums 8 h's, shfl-reduce.
__global__ void prep_v_k(const float* __restrict__ A1W, const float* __restrict__ A2W,
                         float* __restrict__ v) {
  const int dd = blockIdx.x;      // 0..1023
  const int l = threadIdx.x;      // 0..63
  float acc = 0.f;
#pragma unroll
  for (int k = 0; k < 8; ++k) {
    const int h = l + 64 * k;
    acc += A2W[h] * A1W[(size_t)h * (6 * Hs) + 4 * Hs + dd];
  }
#pragma unroll
  for (int off = 32; off > 0; off >>= 1) acc += __shfl_down(acc, off);
  if (l == 0) v[dd] = acc;
}

// Decoder attention (step-invariant): float4 + shuffle reductions; Xe tile
// cached in registers between the score and context passes.
__global__ void dec_ctx_k(const float* __restrict__ Xe, const float* __restrict__ v,
                          const float* __restrict__ yp, const float* __restrict__ fcW,
                          const float* __restrict__ fcb,
                          float* __restrict__ ctx, float* __restrict__ yt) {
  const int b = blockIdx.x;
  const int tid = threadIdx.x;  // 256
  const int lane = tid & 63, wid = tid >> 6;
  const float* xb = Xe + (size_t)b * (T1 * 2 * Hs);
  const int d0 = tid * 4;       // 256*4 = 1024 = 2*Hs
  const float4 v4 = *reinterpret_cast<const float4*>(v + d0);
  float4 x4[T1];
  float s[T1];
#pragma unroll
  for (int t = 0; t < T1; ++t) {
    x4[t] = *reinterpret_cast<const float4*>(xb + t * 2 * Hs + d0);
    s[t] = x4[t].x * v4.x + x4[t].y * v4.y + x4[t].z * v4.z + x4[t].w * v4.w;
  }
  __shared__ float part[T1][4];
  __shared__ float score[T1];
  __shared__ float tot2[4];
  __shared__ float cfs;
#pragma unroll
  for (int t = 0; t < T1; ++t) {
    float r = s[t];
#pragma unroll
    for (int off = 32; off > 0; off >>= 1) r += __shfl_down(r, off);
    if (lane == 0) part[t][wid] = r;
  }
  __syncthreads();
  if (tid < T1) score[tid] = part[tid][0] + part[tid][1] + part[tid][2] + part[tid][3];
  __syncthreads();
  float mx = -1e30f;
#pragma unroll
  for (int t = 0; t < T1; ++t) mx = fmaxf(mx, score[t]);
  float e[T1];
  float sum = 0.f;
#pragma unroll
  for (int t = 0; t < T1; ++t) { e[t] = expf(score[t] - mx); sum += e[t]; }
  const float inv = 1.f / sum;
  float4 c4 = {0.f, 0.f, 0.f, 0.f};
#pragma unroll
  for (int t = 0; t < T1; ++t) {
    c4.x += e[t] * x4[t].x; c4.y += e[t] * x4[t].y;
    c4.z += e[t] * x4[t].z; c4.w += e[t] * x4[t].w;
  }
  c4.x *= inv; c4.y *= inv; c4.z *= inv; c4.w *= inv;
  *reinterpret_cast<float4*>(ctx + (size_t)b * 2 * Hs + d0) = c4;
  const float4 f4 = *reinterpret_cast<const float4*>(fcW + d0);
  float fcacc = c4.x * f4.x + c4.y * f4.y + c4.z * f4.z + c4.w * f4.w;
#pragma unroll
  for (int off = 32; off > 0; off >>= 1) fcacc += __shfl_down(fcacc, off);
  if (lane == 0) tot2[wid] = fcacc;
  __syncthreads();
  if (tid == 0) cfs = tot2[0] + tot2[1] + tot2[2] + tot2[3] + fcb[0];
  __syncthreads();
  if (tid < T1) yt[(size_t)b * T1 + tid] = cfs + yp[(size_t)b * T1 + tid] * fcW[2 * Hs];
}

__global__ void final_out_k(const float* __restrict__ dfin, const float* __restrict__ ctx,
                            const float* __restrict__ Wfin, const float* __restrict__ bfin,
                            float* __restrict__ out) {
  const int b = blockIdx.x;
  const int tid = threadIdx.x;  // 256
  const int lane = tid & 63, wid = tid >> 6;
  const int d0 = tid * 4;
  const float4 a4 = *reinterpret_cast<const float4*>(dfin + (size_t)b * 2 * Hs + d0);
  const float4 w4 = *reinterpret_cast<const float4*>(Wfin + d0);
  const float4 c4 = *reinterpret_cast<const float4*>(ctx + (size_t)b * 2 * Hs + d0);
  const float4 u4 = *reinterpret_cast<const float4*>(Wfin + 2 * Hs + d0);
  float acc = a4.x * w4.x + a4.y * w4.y + a4.z * w4.z + a4.w * w4.w
            + c4.x * u4.x + c4.y * u4.y + c4.z * u4.z + c4.w * u4.w;
#pragma unroll
  for (int off = 32; off > 0; off >>= 1) acc += __shfl_down(acc, off);
  __shared__ float red[4];
  if (lane == 0) red[wid] = acc;
  __syncthreads();
  if (tid == 0) out[b] = red[0] + red[1] + red[2] + red[3] + bfin[0];
}

extern "C" void kernel_launch(void* const* d_in, const int* in_sizes, int n_in,
                              void* d_out, int out_size, void* d_ws, size_t ws_size,
                              hipStream_t stream) {
  const float* X     = (const float*)d_in[0];
  const float* yp    = (const float*)d_in[1];
  const float* encW  = (const float*)d_in[2];
  const float* encb  = (const float*)d_in[3];
  const float* e0Wih = (const float*)d_in[4];
  const float* e0Whh = (const float*)d_in[5];
  const float* e0bih = (const float*)d_in[6];
  const float* e0bhh = (const float*)d_in[7];
  const float* e1Wih = (const float*)d_in[8];
  const float* e1Whh = (const float*)d_in[9];
  const float* e1bih = (const float*)d_in[10];
  const float* e1bhh = (const float*)d_in[11];
  const float* dA1W  = (const float*)d_in[12];
  const float* dA2W  = (const float*)d_in[14];
  const float* dWih  = (const float*)d_in[16];
  const float* dWhh  = (const float*)d_in[17];
  const float* dbih  = (const float*)d_in[18];
  const float* dbhh  = (const float*)d_in[19];
  const float* fcW   = (const float*)d_in[20];
  const float* fcb   = (const float*)d_in[21];
  const float* WfinW = (const float*)d_in[22];
  const float* Wfinb = (const float*)d_in[23];
  float* out = (float*)d_out;
  (void)in_sizes; (void)n_in; (void)out_size; (void)ws_size;

  char* wsb = (char*)d_ws;
  size_t off = 0;
  auto alloc = [&](size_t bytes) -> void* {
    void* p = wsb + off;
    off = (off + bytes + 255) & ~(size_t)255;
    return p;
  };
  const size_t BH  = (size_t)Bsz * Hs;
  const size_t BH2 = (size_t)Bsz * 2 * Hs;
  // No memset needed: FIRST-step kernels never read h/c (write-only at t=0).
  float* c1   = (float*)alloc(BH * 4);
  float* c2   = (float*)alloc(BH * 4);
  float* cdec = (float*)alloc(BH2 * 4);
  bf16* h1hi0 = (bf16*)alloc(BH * 2);
  bf16* h2hi0 = (bf16*)alloc(BH * 2);
  bf16* dhi0  = (bf16*)alloc(BH2 * 2);
  bf16* h1hi1 = (bf16*)alloc(BH * 2);
  bf16* h2hi1 = (bf16*)alloc(BH * 2);
  bf16* dhi1  = (bf16*)alloc(BH2 * 2);
  bf16* W0hi  = (bf16*)alloc((size_t)2048 * 544 * 2);
  bf16* W1hi  = (bf16*)alloc((size_t)2048 * 544 * 2);
  bf16* Wdhi  = (bf16*)alloc((size_t)4096 * 1024 * 2);
  float* bs0  = (float*)alloc(2048 * 4);
  float* bs1  = (float*)alloc(2048 * 4);
  float* bsd  = (float*)alloc(4096 * 4);
  float* wihp = (float*)alloc(4096 * 4);
  bf16* x1h   = (bf16*)alloc((size_t)T1 * Bsz * 32 * 2);
  bf16* x2h   = (bf16*)alloc((size_t)T1 * Bsz * 32 * 2);
  float* Xe   = (float*)alloc((size_t)Bsz * T1 * 2 * Hs * 4);
  float* dfp  = (float*)alloc(BH2 * 4);
  float* ctx  = (float*)alloc(BH2 * 4);
  float* vv   = (float*)alloc(2 * Hs * 4);
  float* yt   = (float*)alloc((size_t)Bsz * T1 * 4);

  build_all_w_k<<<3136, 256, 0, stream>>>(
      e0Whh, e0Wih, e0bih, e0bhh, e1Whh, e1Wih, e1bih, e1bhh,
      dWhh, dWih, dbih, dbhh,
      W0hi, W1hi, Wdhi, bs0, bs1, bsd, wihp);
  prep_attn_k<<<Bsz, 64, 0, stream>>>(X, yp, encW, encb, x1h, x2h);
  prep_v_k<<<2 * Hs, 64, 0, stream>>>(dA1W, dA2W, vv);

  // ---- encoder: 9 steps, both branches per launch ----
  bf16 *h1c = h1hi0, *h1n = h1hi1;
  bf16 *h2c = h2hi0, *h2n = h2hi1;
  for (int t = 0; t < T1; ++t) {
    GA a0{h1c, x1h + (size_t)t * Bsz * 32, W0hi, bs0, nullptr, nullptr,
          c1, h1n, Xe + (size_t)t * 2 * Hs, T1 * 2 * Hs, 0};
    GA a1{h2c, x2h + (size_t)t * Bsz * 32, W1hi, bs1, nullptr, nullptr,
          c2, h2n, Xe + (size_t)t * 2 * Hs + Hs, T1 * 2 * Hs, 0};
    dim3 grid((4 * Hs) / BNP, Bsz / BMT, 2);
    if (t == 0)
      lstm2_k<Hs, 544, true, 2, 512, true><<<grid, 256, 0, stream>>>(a0, a1);
    else
      lstm2_k<Hs, 544, true, 2, 0, false><<<grid, 256, 0, stream>>>(a0, a1);
    bf16* tp;
    tp = h1c; h1c = h1n; h1n = tp;
    tp = h2c; h2c = h2n; h2n = tp;
  }

  dec_ctx_k<<<Bsz, 256, 0, stream>>>(Xe, vv, yp, fcW, fcb, ctx, yt);

  // ---- decoder: 9 steps ----
  bf16 *dc = dhi0, *dn = dhi1;
  for (int t = 0; t < T1; ++t) {
    GA a0{dc, nullptr, Wdhi, bsd, wihp, yt + t,
          cdec, dn, (t == T1 - 1) ? dfp : nullptr, 2 * Hs, T1};
    dim3 grid((8 * Hs) / BNP, Bsz / BMT, 1);
    if (t == 0)
      lstm2_k<2 * Hs, 1024, false, 1, 1024, true><<<grid, 256, 0, stream>>>(a0, a0);
    else
      lstm2_k<2 * Hs, 1024, false, 1, 0, false><<<grid, 256, 0, stream>>>(a0, a0);
    bf16* tp = dc; dc = dn; dn = tp;
  }

  final_out_k<<<Bsz, 256, 0, stream>>>(dfp, ctx, WfinW, Wfinb, out);
}